// Round 8
// baseline (221.866 us; speedup 1.0000x reference)
//
#include <hip/hip_runtime.h>
#include <math.h>

#define NN 50000
#define NE 800000
#define ESLICE 100096   // 391 blocks * 256 threads; 8 slices cover NE

typedef __bf16 bf16x8 __attribute__((ext_vector_type(8)));
typedef __bf16 bf16x4 __attribute__((ext_vector_type(4)));
typedef float f32x4 __attribute__((ext_vector_type(4)));

__device__ __forceinline__ void gload16(const void* g, void* l){
  __builtin_amdgcn_global_load_lds((const __attribute__((address_space(1))) void*)g,
                                   (__attribute__((address_space(3))) void*)l, 16, 0, 0);
}

// ---------------- CSR build ----------------

__global__ void k_zero_i32(int* __restrict__ p, int n){
  int i = blockIdx.x * blockDim.x + threadIdx.x;
  if (i < n) p[i] = 0;
}

__global__ __launch_bounds__(256)
void k_rank(const int* __restrict__ erow, int* __restrict__ cnt, int* __restrict__ pos){
  const int t = blockIdx.x * 256 + threadIdx.x;
  #pragma unroll
  for (int k = 0; k < 8; ++k){
    const int e = t + k * ESLICE;
    if (e < NE){
      const int r = erow[e];
      pos[e] = atomicAdd(&cnt[r], 1);
    }
  }
}

__global__ __launch_bounds__(256)
void k_scan1(const int* __restrict__ cnt, int* __restrict__ rs, int* __restrict__ part, int n){
  const int t = threadIdx.x, b = blockIdx.x;
  const int i = b * 256 + t;
  int v = (i < n) ? cnt[i] : 0;
  const int lane = t & 63, w = t >> 6;
  int s = v;
  #pragma unroll
  for (int d = 1; d < 64; d <<= 1){ int u = __shfl_up(s, d); if (lane >= d) s += u; }
  __shared__ int wsum[4];
  if (lane == 63) wsum[w] = s;
  __syncthreads();
  int add = 0;
  #pragma unroll
  for (int k = 0; k < 4; ++k) if (k < w) add += wsum[k];
  s += add;
  if (i < n) rs[i + 1] = s;
  if (t == 255) part[b] = s;
}

__global__ __launch_bounds__(256)
void k_scan2(int* __restrict__ part, int nb){
  const int t = threadIdx.x;
  int v = (t < nb) ? part[t] : 0;
  const int lane = t & 63, w = t >> 6;
  int s = v;
  #pragma unroll
  for (int d = 1; d < 64; d <<= 1){ int u = __shfl_up(s, d); if (lane >= d) s += u; }
  __shared__ int wsum[4];
  if (lane == 63) wsum[w] = s;
  __syncthreads();
  int add = 0;
  #pragma unroll
  for (int k = 0; k < 4; ++k) if (k < w) add += wsum[k];
  s += add;
  if (t < nb) part[t] = s - v;
}

__global__ __launch_bounds__(256)
void k_scan3(int* __restrict__ rs, const int* __restrict__ part, int n){
  const int i = blockIdx.x * 256 + threadIdx.x;
  if (i < n) rs[i + 1] += part[blockIdx.x];
  if (i == 0) rs[0] = 0;
}

__global__ __launch_bounds__(256)
void k_scatter2(const int* __restrict__ erow, const int* __restrict__ ecol,
                const float* __restrict__ evalv, const int* __restrict__ rs,
                const int* __restrict__ pos, int2* __restrict__ out){
  const int t = blockIdx.x * 256 + threadIdx.x;
  #pragma unroll
  for (int k = 0; k < 8; ++k){
    const int e = t + k * ESLICE;
    if (e < NE){
      const int r = erow[e];
      const int p = rs[r] + pos[e];
      out[p] = make_int2(ecol[e], __float_as_int(evalv[e]));
    }
  }
}

// ---------------- W1 & W2 fp32 -> bf16 (one dispatch) ----------------

__global__ __launch_bounds__(256)
void conv_w(const float* __restrict__ W1, const float* __restrict__ W2,
            __bf16* __restrict__ W1b, __bf16* __restrict__ W2b){
  const int b = blockIdx.x;
  const float* src; __bf16* dst; int q, K, Kp;
  if (b < 80){ src = W1; dst = W1b; q = b * 256 + threadIdx.x; K = 300; Kp = 320; }
  else       { src = W2; dst = W2b; q = (b - 80) * 256 + threadIdx.x; K = 256; Kp = 256; }
  const int perRow = Kp >> 2;
  const int r = q / perRow;
  const int k = (q - r * perRow) << 2;
  float4 v = make_float4(0.f, 0.f, 0.f, 0.f);
  if (k < K) v = *(const float4*)(src + (size_t)r * K + k);
  bf16x4 o;
  o[0] = (__bf16)v.x; o[1] = (__bf16)v.y; o[2] = (__bf16)v.z; o[3] = (__bf16)v.w;
  *(bf16x4*)(dst + (size_t)r * Kp + k) = o;
}

// ---------------- GEMM1: fp32 A (in-kernel cvt, T14 async-split) x bf16 B^T ----------------
// C[Mpad][N] = A32[M][KA] * B[N][ldB]^T. BM=BN=128, BK=64, 4 waves 2x2.
// A: loadA (regs, issued BEFORE compute) ... writeA (cvt + swizzled ds_write, AFTER compute).
// B: global_load_lds. Both-sides XOR swizzle.

template<int KT, int KA>
__global__ __launch_bounds__(256)
void gemm_a32(const float* __restrict__ A32, const __bf16* __restrict__ B,
              __bf16* __restrict__ C, int M, int N, int ldB){
  __shared__ char ldsbuf[65536];                 // 2 x (16KB A + 16KB B)
  const int tid = threadIdx.x;
  const int lane = tid & 63;
  const int bn = blockIdx.x * 128;
  const int bm = blockIdx.y * 128;
  const int wr = (tid >> 7) & 1;
  const int wc = (tid >> 6) & 1;

  f32x4 acc[4][4];
  #pragma unroll
  for (int i = 0; i < 4; ++i)
    #pragma unroll
    for (int j = 0; j < 4; ++j) acc[i][j] = (f32x4){0.f, 0.f, 0.f, 0.f};

  // A: thread -> row ar=tid>>1 (0..127), 32 floats at c0
  const int ar = tid >> 1;
  const int c0 = (tid & 1) * 32;
  const int sw = (ar & 7) << 4;
  const int ga = bm + ar;
  const float* asrc = A32 + (size_t)ga * KA;

  float4 fa[8];

  auto loadA = [&](int kt){
    #pragma unroll
    for (int q = 0; q < 8; ++q){
      const int gk = kt * 64 + c0 + q * 4;
      fa[q] = (ga < M && gk < KA) ? *(const float4*)(asrc + gk)
                                  : make_float4(0.f, 0.f, 0.f, 0.f);
    }
  };

  auto writeA = [&](int sel){
    char* lb = ldsbuf + sel * 32768;
    #pragma unroll
    for (int j = 0; j < 4; ++j){
      bf16x8 h;
      h[0] = (__bf16)fa[2*j].x;   h[1] = (__bf16)fa[2*j].y;
      h[2] = (__bf16)fa[2*j].z;   h[3] = (__bf16)fa[2*j].w;
      h[4] = (__bf16)fa[2*j+1].x; h[5] = (__bf16)fa[2*j+1].y;
      h[6] = (__bf16)fa[2*j+1].z; h[7] = (__bf16)fa[2*j+1].w;
      const int cb = c0 * 2 + j * 16;
      *(bf16x8*)(lb + ar * 128 + (cb ^ sw)) = h;
    }
  };

  auto stageB = [&](int kt, int sel){
    char* lb = ldsbuf + sel * 32768 + 16384;
    #pragma unroll
    for (int i = 0; i < 4; ++i){
      const int d = i * 4096 + tid * 16;
      const int row = d >> 7;
      const int colb = (d & 127) ^ ((row & 7) << 4);
      const __bf16* gp = B + (size_t)(bn + row) * ldB + kt * 64 + (colb >> 1);
      gload16(gp, lb + i * 4096 + (tid & 192) * 16);
    }
  };

  auto compute = [&](int sel){
    const char* lA = ldsbuf + sel * 32768;
    const char* lB = lA + 16384;
    #pragma unroll
    for (int c = 0; c < 2; ++c){
      bf16x8 av[4], bv[4];
      #pragma unroll
      for (int i = 0; i < 4; ++i){
        const int row = wr * 64 + i * 16 + (lane & 15);
        const int colb = (c * 64 + ((lane >> 4) << 4)) ^ ((row & 7) << 4);
        av[i] = *(const bf16x8*)(lA + row * 128 + colb);
      }
      #pragma unroll
      for (int j = 0; j < 4; ++j){
        const int row = wc * 64 + j * 16 + (lane & 15);
        const int colb = (c * 64 + ((lane >> 4) << 4)) ^ ((row & 7) << 4);
        bv[j] = *(const bf16x8*)(lB + row * 128 + colb);
      }
      #pragma unroll
      for (int i = 0; i < 4; ++i)
        #pragma unroll
        for (int j = 0; j < 4; ++j)
          acc[i][j] = __builtin_amdgcn_mfma_f32_16x16x32_bf16(av[i], bv[j], acc[i][j], 0, 0, 0);
    }
  };

  // prologue: stage tile 0 (A write happens immediately; nothing to overlap yet)
  stageB(0, 0);
  loadA(0);
  writeA(0);
  for (int kt = 0; kt < KT; ++kt){
    __syncthreads();                       // buf[kt&1] fully staged (vmcnt+lgkm drained)
    const int sel = kt & 1;
    if (kt + 1 < KT){
      stageB(kt + 1, sel ^ 1);             // async -> LDS
      loadA(kt + 1);                       // async -> regs (issued BEFORE compute)
    }
    compute(sel);                          // MFMA covers the A-load latency
    if (kt + 1 < KT) writeA(sel ^ 1);      // vmcnt wait lands here, after compute
  }

  // epilogue: acc -> LDS bf16 [128][136] -> coalesced bf16x8 stores
  __syncthreads();
  __bf16* lw = (__bf16*)ldsbuf;
  #pragma unroll
  for (int i = 0; i < 4; ++i)
    #pragma unroll
    for (int j = 0; j < 4; ++j)
      #pragma unroll
      for (int r = 0; r < 4; ++r){
        const int row = wr * 64 + i * 16 + ((lane >> 4) << 2) + r;
        const int col = wc * 64 + j * 16 + (lane & 15);
        lw[row * 136 + col] = (__bf16)acc[i][j][r];
      }
  __syncthreads();
  #pragma unroll
  for (int p = 0; p < 8; ++p){
    const int idx = p * 256 + tid;
    const int row = idx >> 4;
    const int c8 = (idx & 15) * 8;
    const bf16x8 o = *(const bf16x8*)&lw[row * 136 + c8];
    *(bf16x8*)(C + (size_t)(bm + row) * N + bn + c8) = o;
  }
}

// ---------------- GEMM2: bf16 x bf16^T -> bf16 (128x128 tile) ----------------

template<int KT>
__global__ __launch_bounds__(256)
void gemm_bf16(const __bf16* __restrict__ A, const __bf16* __restrict__ B,
               __bf16* __restrict__ C, int ld, int N){
  __shared__ char ldsbuf[65536];
  const int tid = threadIdx.x;
  const int lane = tid & 63;
  const int bn = blockIdx.x * 128;
  const int bm = blockIdx.y * 128;
  const int wr = (tid >> 7) & 1;
  const int wc = (tid >> 6) & 1;

  f32x4 acc[4][4];
  #pragma unroll
  for (int i = 0; i < 4; ++i)
    #pragma unroll
    for (int j = 0; j < 4; ++j) acc[i][j] = (f32x4){0.f, 0.f, 0.f, 0.f};

  auto stage = [&](int kt, int sel){
    char* lb = ldsbuf + sel * 32768;
    #pragma unroll
    for (int i = 0; i < 4; ++i){
      const int d = i * 4096 + tid * 16;
      const int row = d >> 7;
      const int colb = (d & 127) ^ ((row & 7) << 4);
      const __bf16* gp = A + (size_t)(bm + row) * ld + kt * 64 + (colb >> 1);
      gload16(gp, lb + i * 4096 + (tid & 192) * 16);
    }
    #pragma unroll
    for (int i = 0; i < 4; ++i){
      const int d = i * 4096 + tid * 16;
      const int row = d >> 7;
      const int colb = (d & 127) ^ ((row & 7) << 4);
      const __bf16* gp = B + (size_t)(bn + row) * ld + kt * 64 + (colb >> 1);
      gload16(gp, lb + 16384 + i * 4096 + (tid & 192) * 16);
    }
  };

  auto compute = [&](int sel){
    const char* lA = ldsbuf + sel * 32768;
    const char* lB = lA + 16384;
    #pragma unroll
    for (int c = 0; c < 2; ++c){
      bf16x8 av[4], bv[4];
      #pragma unroll
      for (int i = 0; i < 4; ++i){
        const int row = wr * 64 + i * 16 + (lane & 15);
        const int colb = (c * 64 + ((lane >> 4) << 4)) ^ ((row & 7) << 4);
        av[i] = *(const bf16x8*)(lA + row * 128 + colb);
      }
      #pragma unroll
      for (int j = 0; j < 4; ++j){
        const int row = wc * 64 + j * 16 + (lane & 15);
        const int colb = (c * 64 + ((lane >> 4) << 4)) ^ ((row & 7) << 4);
        bv[j] = *(const bf16x8*)(lB + row * 128 + colb);
      }
      #pragma unroll
      for (int i = 0; i < 4; ++i)
        #pragma unroll
        for (int j = 0; j < 4; ++j)
          acc[i][j] = __builtin_amdgcn_mfma_f32_16x16x32_bf16(av[i], bv[j], acc[i][j], 0, 0, 0);
    }
  };

  stage(0, 0);
  for (int kt = 0; kt < KT; ++kt){
    __syncthreads();
    if (kt + 1 < KT) stage(kt + 1, (kt + 1) & 1);
    compute(kt & 1);
  }

  __syncthreads();
  __bf16* lw = (__bf16*)ldsbuf;
  #pragma unroll
  for (int i = 0; i < 4; ++i)
    #pragma unroll
    for (int j = 0; j < 4; ++j)
      #pragma unroll
      for (int r = 0; r < 4; ++r){
        const int row = wr * 64 + i * 16 + ((lane >> 4) << 2) + r;
        const int col = wc * 64 + j * 16 + (lane & 15);
        lw[row * 136 + col] = (__bf16)acc[i][j][r];
      }
  __syncthreads();
  #pragma unroll
  for (int p = 0; p < 8; ++p){
    const int idx = p * 256 + tid;
    const int row = idx >> 4;
    const int c8 = (idx & 15) * 8;
    const bf16x8 o = *(const bf16x8*)&lw[row * 136 + c8];
    *(bf16x8*)(C + (size_t)(bm + row) * N + bn + c8) = o;
  }
}

// ---------------- SpMM (CSR, wave per row, 16-lane/edge quarters, x4 unroll) ----------------

__global__ __launch_bounds__(256)
void spmm_relu_half(const int2* __restrict__ ecv, const int* __restrict__ start,
                    const __bf16* __restrict__ H, const float* __restrict__ bias,
                    __bf16* __restrict__ out, int ch0){
  const int w = (blockIdx.x * 256 + threadIdx.x) >> 6;
  const int lane = threadIdx.x & 63;
  const int quar = lane >> 4, sl = lane & 15;
  if (w >= NN) return;
  const int s = start[w], e = start[w + 1];
  float a[8];
  #pragma unroll
  for (int k = 0; k < 8; ++k) a[k] = 0.f;
  for (int base = s; base < e; base += 64){
    int2 cv = make_int2(0, 0);
    if (base + lane < e) cv = ecv[base + lane];
    const int m = min(64, e - base);
    for (int j2 = 0; 16 * j2 < m; ++j2){
      int cc[4]; float vv[4];
      #pragma unroll
      for (int u = 0; u < 4; ++u){
        const int idx = 16 * j2 + quar + 4 * u;
        cc[u] = __shfl(cv.x, idx);
        vv[u] = __int_as_float(__shfl(cv.y, idx));
        if (idx >= m){ cc[u] = 0; vv[u] = 0.f; }
      }
      bf16x8 h[4];
      #pragma unroll
      for (int u = 0; u < 4; ++u)
        h[u] = *(const bf16x8*)(H + (size_t)cc[u] * 256 + ch0 + sl * 8);
      #pragma unroll
      for (int u = 0; u < 4; ++u)
        #pragma unroll
        for (int k = 0; k < 8; ++k) a[k] = fmaf(vv[u], (float)h[u][k], a[k]);
    }
  }
  #pragma unroll
  for (int k = 0; k < 8; ++k){
    a[k] += __shfl_xor(a[k], 32);
    a[k] += __shfl_xor(a[k], 16);
  }
  const float4 b0 = *(const float4*)(bias + ch0 + sl * 8);
  const float4 b1 = *(const float4*)(bias + ch0 + sl * 8 + 4);
  bf16x8 o;
  o[0] = (__bf16)fmaxf(a[0] + b0.x, 0.f);
  o[1] = (__bf16)fmaxf(a[1] + b0.y, 0.f);
  o[2] = (__bf16)fmaxf(a[2] + b0.z, 0.f);
  o[3] = (__bf16)fmaxf(a[3] + b0.w, 0.f);
  o[4] = (__bf16)fmaxf(a[4] + b1.x, 0.f);
  o[5] = (__bf16)fmaxf(a[5] + b1.y, 0.f);
  o[6] = (__bf16)fmaxf(a[6] + b1.z, 0.f);
  o[7] = (__bf16)fmaxf(a[7] + b1.w, 0.f);
  if (quar == 0) *(bf16x8*)(out + (size_t)w * 256 + ch0 + sl * 8) = o;
}

__global__ __launch_bounds__(256)
void spmm_bias_norm_b16(const int2* __restrict__ ecv, const int* __restrict__ start,
                        const __bf16* __restrict__ H, const float* __restrict__ bias,
                        float* __restrict__ out){
  const int w = (blockIdx.x * 256 + threadIdx.x) >> 6;
  const int lane = threadIdx.x & 63;
  const int quar = lane >> 4, sl = lane & 15;
  if (w >= NN) return;
  const int s = start[w], e = start[w + 1];
  float a[8];
  #pragma unroll
  for (int k = 0; k < 8; ++k) a[k] = 0.f;
  for (int base = s; base < e; base += 64){
    int2 cv = make_int2(0, 0);
    if (base + lane < e) cv = ecv[base + lane];
    const int m = min(64, e - base);
    for (int j2 = 0; 16 * j2 < m; ++j2){
      int cc[4]; float vv[4];
      #pragma unroll
      for (int u = 0; u < 4; ++u){
        const int idx = 16 * j2 + quar + 4 * u;
        cc[u] = __shfl(cv.x, idx);
        vv[u] = __int_as_float(__shfl(cv.y, idx));
        if (idx >= m){ cc[u] = 0; vv[u] = 0.f; }
      }
      bf16x8 h[4];
      #pragma unroll
      for (int u = 0; u < 4; ++u)
        h[u] = *(const bf16x8*)(H + (size_t)cc[u] * 128 + sl * 8);
      #pragma unroll
      for (int u = 0; u < 4; ++u)
        #pragma unroll
        for (int k = 0; k < 8; ++k) a[k] = fmaf(vv[u], (float)h[u][k], a[k]);
    }
  }
  #pragma unroll
  for (int k = 0; k < 8; ++k){
    a[k] += __shfl_xor(a[k], 32);
    a[k] += __shfl_xor(a[k], 16);
  }
  const float4 b0 = *(const float4*)(bias + sl * 8);
  const float4 b1 = *(const float4*)(bias + sl * 8 + 4);
  float f[8];
  f[0] = a[0] + b0.x; f[1] = a[1] + b0.y; f[2] = a[2] + b0.z; f[3] = a[3] + b0.w;
  f[4] = a[4] + b1.x; f[5] = a[5] + b1.y; f[6] = a[6] + b1.z; f[7] = a[7] + b1.w;
  float ss = 0.f;
  #pragma unroll
  for (int k = 0; k < 8; ++k) ss = fmaf(f[k], f[k], ss);
  #pragma unroll
  for (int m2 = 1; m2 < 16; m2 <<= 1) ss += __shfl_xor(ss, m2);
  const float inv = 1.f / fmaxf(sqrtf(ss), 1e-12f);
  if (quar == 0){
    float4 o0 = make_float4(f[0] * inv, f[1] * inv, f[2] * inv, f[3] * inv);
    float4 o1 = make_float4(f[4] * inv, f[5] * inv, f[6] * inv, f[7] * inv);
    *(float4*)(out + (size_t)w * 128 + sl * 8) = o0;
    *(float4*)(out + (size_t)w * 128 + sl * 8 + 4) = o1;
  }
}

// ---------------- launch ----------------
// ws layout (bytes):
//  W1b @ 0          [256][320] bf16  =    163,840
//  W2b @ 163840     [128][256] bf16  =     65,536
//  h1  @ 229376     [50048][256]bf16 = 25,624,576  (pos[800000] aliases head in CSR build)
//  h2  @ 25853952   [50048][256]bf16 = 25,624,576
//  h3  @ 51478528   [50048][128]bf16 = 12,812,288
//  ecv @ 64290816   800000 int2      =  6,400,000
//  rs  @ 70690816   50001 int        =    200,016
//  part@ 70890832   ~200 int
//  cur @ 70892416   50000 int        =    200,000   total ~71.1 MB

extern "C" void kernel_launch(void* const* d_in, const int* in_sizes, int n_in,
                              void* d_out, int out_size, void* d_ws, size_t ws_size,
                              hipStream_t stream){
  const float* x    = (const float*)d_in[0];
  const int*   erow = (const int*)d_in[1];
  const int*   ecol = (const int*)d_in[2];
  const float* evalv= (const float*)d_in[3];
  const float* W1   = (const float*)d_in[4];
  const float* b1   = (const float*)d_in[5];
  const float* W2   = (const float*)d_in[6];
  const float* b2   = (const float*)d_in[7];
  float* out = (float*)d_out;

  char* ws = (char*)d_ws;
  __bf16* W1b = (__bf16*)(ws);
  __bf16* W2b = (__bf16*)(ws + 163840);
  __bf16* h1  = (__bf16*)(ws + 229376);
  __bf16* h2  = (__bf16*)(ws + 25853952);
  __bf16* h3  = (__bf16*)(ws + 51478528);
  int2*   ecv = (int2*)(ws + 64290816);
  int*    rs  = (int*)(ws + 70690816);
  int*    part= (int*)(ws + 70890832);
  int*    cur = (int*)(ws + 70892416);
  int*    pos = (int*)(ws + 229376);     // aliases h1 head (dead until gemm1)

  // CSR build: rank(+hist) -> scan -> atomic-free scatter
  k_zero_i32<<<196, 256, 0, stream>>>(cur, NN);
  k_rank<<<391, 256, 0, stream>>>(erow, cur, pos);
  k_scan1<<<196, 256, 0, stream>>>(cur, rs, part, NN);
  k_scan2<<<1, 256, 0, stream>>>(part, 196);
  k_scan3<<<196, 256, 0, stream>>>(rs, part, NN);
  k_scatter2<<<391, 256, 0, stream>>>(erow, ecol, evalv, rs, pos, ecv);

  // weight conversions (one dispatch)
  conv_w<<<112, 256, 0, stream>>>(W1, W2, W1b, W2b);

  // layer 1: h1 = bf16(x @ W1^T) fused cvt (T14 split); h2 = bf16(relu(A*h1+b1)) in 2 halves
  gemm_a32<5, 300><<<dim3(2, 391), 256, 0, stream>>>(x, W1b, h1, NN, 256, 320);
  spmm_relu_half<<<12500, 256, 0, stream>>>(ecv, rs, h1, b1, h2, 0);
  spmm_relu_half<<<12500, 256, 0, stream>>>(ecv, rs, h1, b1, h2, 128);

  // layer 2: h3 = bf16(h2 @ W2b^T); out = l2norm(A*h3 + b2)
  gemm_bf16<4><<<dim3(1, 391), 256, 0, stream>>>(h2, W2b, h3, 256, 128);
  spmm_bias_norm_b16<<<12500, 256, 0, stream>>>(ecv, rs, h3, b2, out);
}

// Round 9
// 204.515 us; speedup vs baseline: 1.0848x; 1.0848x over previous
//
#include <hip/hip_runtime.h>
#include <math.h>

#define NN 50000
#define NE 800000
#define ESLICE 100096   // 391 blocks * 256 threads; 8 slices cover NE

typedef __bf16 bf16x8 __attribute__((ext_vector_type(8)));
typedef __bf16 bf16x4 __attribute__((ext_vector_type(4)));
typedef float f32x4 __attribute__((ext_vector_type(4)));

__device__ __forceinline__ void gload16(const void* g, void* l){
  __builtin_amdgcn_global_load_lds((const __attribute__((address_space(1))) void*)g,
                                   (__attribute__((address_space(3))) void*)l, 16, 0, 0);
}

// ---------------- CSR build ----------------

__global__ void k_zero_i32(int* __restrict__ p, int n){
  int i = blockIdx.x * blockDim.x + threadIdx.x;
  if (i < n) p[i] = 0;
}

__global__ __launch_bounds__(256)
void k_rank(const int* __restrict__ erow, int* __restrict__ cnt, int* __restrict__ pos){
  const int t = blockIdx.x * 256 + threadIdx.x;
  #pragma unroll
  for (int k = 0; k < 8; ++k){
    const int e = t + k * ESLICE;
    if (e < NE){
      const int r = erow[e];
      pos[e] = atomicAdd(&cnt[r], 1);
    }
  }
}

__global__ __launch_bounds__(256)
void k_scan1(const int* __restrict__ cnt, int* __restrict__ rs, int* __restrict__ part, int n){
  const int t = threadIdx.x, b = blockIdx.x;
  const int i = b * 256 + t;
  int v = (i < n) ? cnt[i] : 0;
  const int lane = t & 63, w = t >> 6;
  int s = v;
  #pragma unroll
  for (int d = 1; d < 64; d <<= 1){ int u = __shfl_up(s, d); if (lane >= d) s += u; }
  __shared__ int wsum[4];
  if (lane == 63) wsum[w] = s;
  __syncthreads();
  int add = 0;
  #pragma unroll
  for (int k = 0; k < 4; ++k) if (k < w) add += wsum[k];
  s += add;
  if (i < n) rs[i + 1] = s;
  if (t == 255) part[b] = s;
}

__global__ __launch_bounds__(256)
void k_scan2(int* __restrict__ part, int nb){
  const int t = threadIdx.x;
  int v = (t < nb) ? part[t] : 0;
  const int lane = t & 63, w = t >> 6;
  int s = v;
  #pragma unroll
  for (int d = 1; d < 64; d <<= 1){ int u = __shfl_up(s, d); if (lane >= d) s += u; }
  __shared__ int wsum[4];
  if (lane == 63) wsum[w] = s;
  __syncthreads();
  int add = 0;
  #pragma unroll
  for (int k = 0; k < 4; ++k) if (k < w) add += wsum[k];
  s += add;
  if (t < nb) part[t] = s - v;
}

__global__ __launch_bounds__(256)
void k_scan3(int* __restrict__ rs, const int* __restrict__ part, int n){
  const int i = blockIdx.x * 256 + threadIdx.x;
  if (i < n) rs[i + 1] += part[blockIdx.x];
  if (i == 0) rs[0] = 0;
}

__global__ __launch_bounds__(256)
void k_scatter2(const int* __restrict__ erow, const int* __restrict__ ecol,
                const float* __restrict__ evalv, const int* __restrict__ rs,
                const int* __restrict__ pos, int2* __restrict__ out){
  const int t = blockIdx.x * 256 + threadIdx.x;
  #pragma unroll
  for (int k = 0; k < 8; ++k){
    const int e = t + k * ESLICE;
    if (e < NE){
      const int r = erow[e];
      const int p = rs[r] + pos[e];
      out[p] = make_int2(ecol[e], __float_as_int(evalv[e]));
    }
  }
}

// ---------------- W1 & W2 fp32 -> bf16 (one dispatch) ----------------

__global__ __launch_bounds__(256)
void conv_w(const float* __restrict__ W1, const float* __restrict__ W2,
            __bf16* __restrict__ W1b, __bf16* __restrict__ W2b){
  const int b = blockIdx.x;
  const float* src; __bf16* dst; int q, K, Kp;
  if (b < 80){ src = W1; dst = W1b; q = b * 256 + threadIdx.x; K = 300; Kp = 320; }
  else       { src = W2; dst = W2b; q = (b - 80) * 256 + threadIdx.x; K = 256; Kp = 256; }
  const int perRow = Kp >> 2;
  const int r = q / perRow;
  const int k = (q - r * perRow) << 2;
  float4 v = make_float4(0.f, 0.f, 0.f, 0.f);
  if (k < K) v = *(const float4*)(src + (size_t)r * K + k);
  bf16x4 o;
  o[0] = (__bf16)v.x; o[1] = (__bf16)v.y; o[2] = (__bf16)v.z; o[3] = (__bf16)v.w;
  *(bf16x4*)(dst + (size_t)r * Kp + k) = o;
}

// ---------------- GEMM1: fp32 A (in-kernel cvt) x bf16 B^T -> bf16 C ----------------
// C[Mpad][N] = A32[M][KA] * B[N][ldB]^T. BM=BN=128, BK=64, 4 waves 2x2.
// A: DENSE per-instruction loads (16 lanes x 16B contiguous per row chunk) into regs
//    issued BEFORE compute; cvt + swizzled ds_write_b64 AFTER compute (T14 split).
// B: global_load_lds. Both-sides XOR swizzle.

template<int KT, int KA>
__global__ __launch_bounds__(256)
void gemm_a32(const float* __restrict__ A32, const __bf16* __restrict__ B,
              __bf16* __restrict__ C, int M, int N, int ldB){
  __shared__ char ldsbuf[65536];                 // 2 x (16KB A + 16KB B)
  const int tid = threadIdx.x;
  const int lane = tid & 63;
  const int bn = blockIdx.x * 128;
  const int bm = blockIdx.y * 128;
  const int wr = (tid >> 7) & 1;
  const int wc = (tid >> 6) & 1;

  f32x4 acc[4][4];
  #pragma unroll
  for (int i = 0; i < 4; ++i)
    #pragma unroll
    for (int j = 0; j < 4; ++j) acc[i][j] = (f32x4){0.f, 0.f, 0.f, 0.f};

  // A map: sub-load q covers flat float4 idx q*256+tid of the 128x64f chunk:
  //   row = q*16 + (tid>>4), c4 = tid&15  -> per instr: 4 rows x 256B dense.
  const int arow = tid >> 4;     // 0..15
  const int ac4  = tid & 15;     // float4 index within the 64-float row chunk

  float4 fa[8];

  auto loadA = [&](int kt){
    #pragma unroll
    for (int q = 0; q < 8; ++q){
      const int r = q * 16 + arow;
      const int g = bm + r;
      const int gk = kt * 64 + ac4 * 4;
      fa[q] = (g < M && gk + 4 <= KA) ? *(const float4*)(A32 + (size_t)g * KA + gk)
                                      : make_float4(0.f, 0.f, 0.f, 0.f);
    }
  };

  auto writeA = [&](int sel){
    char* lb = ldsbuf + sel * 32768;
    #pragma unroll
    for (int q = 0; q < 8; ++q){
      const int r = q * 16 + arow;
      bf16x4 h;
      h[0] = (__bf16)fa[q].x; h[1] = (__bf16)fa[q].y;
      h[2] = (__bf16)fa[q].z; h[3] = (__bf16)fa[q].w;
      const int cb = ac4 * 8;                    // byte col in 128B bf16 row
      *(bf16x4*)(lb + r * 128 + (cb ^ ((r & 7) << 4))) = h;
    }
  };

  auto stageB = [&](int kt, int sel){
    char* lb = ldsbuf + sel * 32768 + 16384;
    #pragma unroll
    for (int i = 0; i < 4; ++i){
      const int d = i * 4096 + tid * 16;
      const int row = d >> 7;
      const int colb = (d & 127) ^ ((row & 7) << 4);
      const __bf16* gp = B + (size_t)(bn + row) * ldB + kt * 64 + (colb >> 1);
      gload16(gp, lb + i * 4096 + (tid & 192) * 16);
    }
  };

  auto compute = [&](int sel){
    const char* lA = ldsbuf + sel * 32768;
    const char* lB = lA + 16384;
    #pragma unroll
    for (int c = 0; c < 2; ++c){
      bf16x8 av[4], bv[4];
      #pragma unroll
      for (int i = 0; i < 4; ++i){
        const int row = wr * 64 + i * 16 + (lane & 15);
        const int colb = (c * 64 + ((lane >> 4) << 4)) ^ ((row & 7) << 4);
        av[i] = *(const bf16x8*)(lA + row * 128 + colb);
      }
      #pragma unroll
      for (int j = 0; j < 4; ++j){
        const int row = wc * 64 + j * 16 + (lane & 15);
        const int colb = (c * 64 + ((lane >> 4) << 4)) ^ ((row & 7) << 4);
        bv[j] = *(const bf16x8*)(lB + row * 128 + colb);
      }
      #pragma unroll
      for (int i = 0; i < 4; ++i)
        #pragma unroll
        for (int j = 0; j < 4; ++j)
          acc[i][j] = __builtin_amdgcn_mfma_f32_16x16x32_bf16(av[i], bv[j], acc[i][j], 0, 0, 0);
    }
  };

  // prologue
  stageB(0, 0);
  loadA(0);
  writeA(0);
  for (int kt = 0; kt < KT; ++kt){
    __syncthreads();                       // buf[kt&1] fully staged
    const int sel = kt & 1;
    if (kt + 1 < KT){
      stageB(kt + 1, sel ^ 1);             // async -> LDS
      loadA(kt + 1);                       // async -> regs (issued BEFORE compute)
    }
    compute(sel);                          // MFMA covers the A-load latency
    if (kt + 1 < KT) writeA(sel ^ 1);      // vmcnt wait lands here, after compute
  }

  // epilogue: acc -> LDS bf16 [128][136] -> coalesced bf16x8 stores
  __syncthreads();
  __bf16* lw = (__bf16*)ldsbuf;
  #pragma unroll
  for (int i = 0; i < 4; ++i)
    #pragma unroll
    for (int j = 0; j < 4; ++j)
      #pragma unroll
      for (int r = 0; r < 4; ++r){
        const int row = wr * 64 + i * 16 + ((lane >> 4) << 2) + r;
        const int col = wc * 64 + j * 16 + (lane & 15);
        lw[row * 136 + col] = (__bf16)acc[i][j][r];
      }
  __syncthreads();
  #pragma unroll
  for (int p = 0; p < 8; ++p){
    const int idx = p * 256 + tid;
    const int row = idx >> 4;
    const int c8 = (idx & 15) * 8;
    const bf16x8 o = *(const bf16x8*)&lw[row * 136 + c8];
    *(bf16x8*)(C + (size_t)(bm + row) * N + bn + c8) = o;
  }
}

// ---------------- GEMM2: bf16 x bf16^T -> bf16 (128x128 tile) ----------------

template<int KT>
__global__ __launch_bounds__(256)
void gemm_bf16(const __bf16* __restrict__ A, const __bf16* __restrict__ B,
               __bf16* __restrict__ C, int ld, int N){
  __shared__ char ldsbuf[65536];
  const int tid = threadIdx.x;
  const int lane = tid & 63;
  const int bn = blockIdx.x * 128;
  const int bm = blockIdx.y * 128;
  const int wr = (tid >> 7) & 1;
  const int wc = (tid >> 6) & 1;

  f32x4 acc[4][4];
  #pragma unroll
  for (int i = 0; i < 4; ++i)
    #pragma unroll
    for (int j = 0; j < 4; ++j) acc[i][j] = (f32x4){0.f, 0.f, 0.f, 0.f};

  auto stage = [&](int kt, int sel){
    char* lb = ldsbuf + sel * 32768;
    #pragma unroll
    for (int i = 0; i < 4; ++i){
      const int d = i * 4096 + tid * 16;
      const int row = d >> 7;
      const int colb = (d & 127) ^ ((row & 7) << 4);
      const __bf16* gp = A + (size_t)(bm + row) * ld + kt * 64 + (colb >> 1);
      gload16(gp, lb + i * 4096 + (tid & 192) * 16);
    }
    #pragma unroll
    for (int i = 0; i < 4; ++i){
      const int d = i * 4096 + tid * 16;
      const int row = d >> 7;
      const int colb = (d & 127) ^ ((row & 7) << 4);
      const __bf16* gp = B + (size_t)(bn + row) * ld + kt * 64 + (colb >> 1);
      gload16(gp, lb + 16384 + i * 4096 + (tid & 192) * 16);
    }
  };

  auto compute = [&](int sel){
    const char* lA = ldsbuf + sel * 32768;
    const char* lB = lA + 16384;
    #pragma unroll
    for (int c = 0; c < 2; ++c){
      bf16x8 av[4], bv[4];
      #pragma unroll
      for (int i = 0; i < 4; ++i){
        const int row = wr * 64 + i * 16 + (lane & 15);
        const int colb = (c * 64 + ((lane >> 4) << 4)) ^ ((row & 7) << 4);
        av[i] = *(const bf16x8*)(lA + row * 128 + colb);
      }
      #pragma unroll
      for (int j = 0; j < 4; ++j){
        const int row = wc * 64 + j * 16 + (lane & 15);
        const int colb = (c * 64 + ((lane >> 4) << 4)) ^ ((row & 7) << 4);
        bv[j] = *(const bf16x8*)(lB + row * 128 + colb);
      }
      #pragma unroll
      for (int i = 0; i < 4; ++i)
        #pragma unroll
        for (int j = 0; j < 4; ++j)
          acc[i][j] = __builtin_amdgcn_mfma_f32_16x16x32_bf16(av[i], bv[j], acc[i][j], 0, 0, 0);
    }
  };

  stage(0, 0);
  for (int kt = 0; kt < KT; ++kt){
    __syncthreads();
    if (kt + 1 < KT) stage(kt + 1, (kt + 1) & 1);
    compute(kt & 1);
  }

  __syncthreads();
  __bf16* lw = (__bf16*)ldsbuf;
  #pragma unroll
  for (int i = 0; i < 4; ++i)
    #pragma unroll
    for (int j = 0; j < 4; ++j)
      #pragma unroll
      for (int r = 0; r < 4; ++r){
        const int row = wr * 64 + i * 16 + ((lane >> 4) << 2) + r;
        const int col = wc * 64 + j * 16 + (lane & 15);
        lw[row * 136 + col] = (__bf16)acc[i][j][r];
      }
  __syncthreads();
  #pragma unroll
  for (int p = 0; p < 8; ++p){
    const int idx = p * 256 + tid;
    const int row = idx >> 4;
    const int c8 = (idx & 15) * 8;
    const bf16x8 o = *(const bf16x8*)&lw[row * 136 + c8];
    *(bf16x8*)(C + (size_t)(bm + row) * N + bn + c8) = o;
  }
}

// ---------------- SpMM (CSR, wave per row, 16-lane/edge quarters, x4 unroll) ----------------

__global__ __launch_bounds__(256)
void spmm_relu_half(const int2* __restrict__ ecv, const int* __restrict__ start,
                    const __bf16* __restrict__ H, const float* __restrict__ bias,
                    __bf16* __restrict__ out, int ch0){
  const int w = (blockIdx.x * 256 + threadIdx.x) >> 6;
  const int lane = threadIdx.x & 63;
  const int quar = lane >> 4, sl = lane & 15;
  if (w >= NN) return;
  const int s = start[w], e = start[w + 1];
  float a[8];
  #pragma unroll
  for (int k = 0; k < 8; ++k) a[k] = 0.f;
  for (int base = s; base < e; base += 64){
    int2 cv = make_int2(0, 0);
    if (base + lane < e) cv = ecv[base + lane];
    const int m = min(64, e - base);
    for (int j2 = 0; 16 * j2 < m; ++j2){
      int cc[4]; float vv[4];
      #pragma unroll
      for (int u = 0; u < 4; ++u){
        const int idx = 16 * j2 + quar + 4 * u;
        cc[u] = __shfl(cv.x, idx);
        vv[u] = __int_as_float(__shfl(cv.y, idx));
        if (idx >= m){ cc[u] = 0; vv[u] = 0.f; }
      }
      bf16x8 h[4];
      #pragma unroll
      for (int u = 0; u < 4; ++u)
        h[u] = *(const bf16x8*)(H + (size_t)cc[u] * 256 + ch0 + sl * 8);
      #pragma unroll
      for (int u = 0; u < 4; ++u)
        #pragma unroll
        for (int k = 0; k < 8; ++k) a[k] = fmaf(vv[u], (float)h[u][k], a[k]);
    }
  }
  #pragma unroll
  for (int k = 0; k < 8; ++k){
    a[k] += __shfl_xor(a[k], 32);
    a[k] += __shfl_xor(a[k], 16);
  }
  const float4 b0 = *(const float4*)(bias + ch0 + sl * 8);
  const float4 b1 = *(const float4*)(bias + ch0 + sl * 8 + 4);
  bf16x8 o;
  o[0] = (__bf16)fmaxf(a[0] + b0.x, 0.f);
  o[1] = (__bf16)fmaxf(a[1] + b0.y, 0.f);
  o[2] = (__bf16)fmaxf(a[2] + b0.z, 0.f);
  o[3] = (__bf16)fmaxf(a[3] + b0.w, 0.f);
  o[4] = (__bf16)fmaxf(a[4] + b1.x, 0.f);
  o[5] = (__bf16)fmaxf(a[5] + b1.y, 0.f);
  o[6] = (__bf16)fmaxf(a[6] + b1.z, 0.f);
  o[7] = (__bf16)fmaxf(a[7] + b1.w, 0.f);
  if (quar == 0) *(bf16x8*)(out + (size_t)w * 256 + ch0 + sl * 8) = o;
}

__global__ __launch_bounds__(256)
void spmm_bias_norm_b16(const int2* __restrict__ ecv, const int* __restrict__ start,
                        const __bf16* __restrict__ H, const float* __restrict__ bias,
                        float* __restrict__ out){
  const int w = (blockIdx.x * 256 + threadIdx.x) >> 6;
  const int lane = threadIdx.x & 63;
  const int quar = lane >> 4, sl = lane & 15;
  if (w >= NN) return;
  const int s = start[w], e = start[w + 1];
  float a[8];
  #pragma unroll
  for (int k = 0; k < 8; ++k) a[k] = 0.f;
  for (int base = s; base < e; base += 64){
    int2 cv = make_int2(0, 0);
    if (base + lane < e) cv = ecv[base + lane];
    const int m = min(64, e - base);
    for (int j2 = 0; 16 * j2 < m; ++j2){
      int cc[4]; float vv[4];
      #pragma unroll
      for (int u = 0; u < 4; ++u){
        const int idx = 16 * j2 + quar + 4 * u;
        cc[u] = __shfl(cv.x, idx);
        vv[u] = __int_as_float(__shfl(cv.y, idx));
        if (idx >= m){ cc[u] = 0; vv[u] = 0.f; }
      }
      bf16x8 h[4];
      #pragma unroll
      for (int u = 0; u < 4; ++u)
        h[u] = *(const bf16x8*)(H + (size_t)cc[u] * 128 + sl * 8);
      #pragma unroll
      for (int u = 0; u < 4; ++u)
        #pragma unroll
        for (int k = 0; k < 8; ++k) a[k] = fmaf(vv[u], (float)h[u][k], a[k]);
    }
  }
  #pragma unroll
  for (int k = 0; k < 8; ++k){
    a[k] += __shfl_xor(a[k], 32);
    a[k] += __shfl_xor(a[k], 16);
  }
  const float4 b0 = *(const float4*)(bias + sl * 8);
  const float4 b1 = *(const float4*)(bias + sl * 8 + 4);
  float f[8];
  f[0] = a[0] + b0.x; f[1] = a[1] + b0.y; f[2] = a[2] + b0.z; f[3] = a[3] + b0.w;
  f[4] = a[4] + b1.x; f[5] = a[5] + b1.y; f[6] = a[6] + b1.z; f[7] = a[7] + b1.w;
  float ss = 0.f;
  #pragma unroll
  for (int k = 0; k < 8; ++k) ss = fmaf(f[k], f[k], ss);
  #pragma unroll
  for (int m2 = 1; m2 < 16; m2 <<= 1) ss += __shfl_xor(ss, m2);
  const float inv = 1.f / fmaxf(sqrtf(ss), 1e-12f);
  if (quar == 0){
    float4 o0 = make_float4(f[0] * inv, f[1] * inv, f[2] * inv, f[3] * inv);
    float4 o1 = make_float4(f[4] * inv, f[5] * inv, f[6] * inv, f[7] * inv);
    *(float4*)(out + (size_t)w * 128 + sl * 8) = o0;
    *(float4*)(out + (size_t)w * 128 + sl * 8 + 4) = o1;
  }
}

// ---------------- launch ----------------
// ws layout (bytes):
//  W1b @ 0          [256][320] bf16  =    163,840
//  W2b @ 163840     [128][256] bf16  =     65,536
//  h1  @ 229376     [50048][256]bf16 = 25,624,576  (pos[800000] aliases head in CSR build)
//  h2  @ 25853952   [50048][256]bf16 = 25,624,576
//  h3  @ 51478528   [50048][128]bf16 = 12,812,288
//  ecv @ 64290816   800000 int2      =  6,400,000
//  rs  @ 70690816   50001 int        =    200,016
//  part@ 70890832   ~200 int
//  cur @ 70892416   50000 int        =    200,000   total ~71.1 MB

extern "C" void kernel_launch(void* const* d_in, const int* in_sizes, int n_in,
                              void* d_out, int out_size, void* d_ws, size_t ws_size,
                              hipStream_t stream){
  const float* x    = (const float*)d_in[0];
  const int*   erow = (const int*)d_in[1];
  const int*   ecol = (const int*)d_in[2];
  const float* evalv= (const float*)d_in[3];
  const float* W1   = (const float*)d_in[4];
  const float* b1   = (const float*)d_in[5];
  const float* W2   = (const float*)d_in[6];
  const float* b2   = (const float*)d_in[7];
  float* out = (float*)d_out;

  char* ws = (char*)d_ws;
  __bf16* W1b = (__bf16*)(ws);
  __bf16* W2b = (__bf16*)(ws + 163840);
  __bf16* h1  = (__bf16*)(ws + 229376);
  __bf16* h2  = (__bf16*)(ws + 25853952);
  __bf16* h3  = (__bf16*)(ws + 51478528);
  int2*   ecv = (int2*)(ws + 64290816);
  int*    rs  = (int*)(ws + 70690816);
  int*    part= (int*)(ws + 70890832);
  int*    cur = (int*)(ws + 70892416);
  int*    pos = (int*)(ws + 229376);     // aliases h1 head (dead until gemm1)

  // CSR build: rank(+hist) -> scan -> atomic-free scatter
  k_zero_i32<<<196, 256, 0, stream>>>(cur, NN);
  k_rank<<<391, 256, 0, stream>>>(erow, cur, pos);
  k_scan1<<<196, 256, 0, stream>>>(cur, rs, part, NN);
  k_scan2<<<1, 256, 0, stream>>>(part, 196);
  k_scan3<<<196, 256, 0, stream>>>(rs, part, NN);
  k_scatter2<<<391, 256, 0, stream>>>(erow, ecol, evalv, rs, pos, ecv);

  // weight conversions (one dispatch)
  conv_w<<<112, 256, 0, stream>>>(W1, W2, W1b, W2b);

  // layer 1: h1 = bf16(x @ W1^T) fused cvt (dense loads + T14); h2 in 2 halves
  gemm_a32<5, 300><<<dim3(2, 391), 256, 0, stream>>>(x, W1b, h1, NN, 256, 320);
  spmm_relu_half<<<12500, 256, 0, stream>>>(ecv, rs, h1, b1, h2, 0);
  spmm_relu_half<<<12500, 256, 0, stream>>>(ecv, rs, h1, b1, h2, 128);

  // layer 2: h3 = bf16(h2 @ W2b^T); out = l2norm(A*h3 + b2)
  gemm_bf16<4><<<dim3(1, 391), 256, 0, stream>>>(h2, W2b, h3, 256, 128);
  spmm_bias_norm_b16<<<12500, 256, 0, stream>>>(ecv, rs, h3, b2, out);
}

// Round 10
// 197.418 us; speedup vs baseline: 1.1238x; 1.0359x over previous
//
#include <hip/hip_runtime.h>
#include <math.h>

#define NN 50000
#define NE 800000
#define ESLICE 100096   // 391 blocks * 256 threads; 8 slices cover NE

typedef __bf16 bf16x8 __attribute__((ext_vector_type(8)));
typedef __bf16 bf16x4 __attribute__((ext_vector_type(4)));
typedef float f32x4 __attribute__((ext_vector_type(4)));

__device__ __forceinline__ void gload16(const void* g, void* l){
  __builtin_amdgcn_global_load_lds((const __attribute__((address_space(1))) void*)g,
                                   (__attribute__((address_space(3))) void*)l, 16, 0, 0);
}

// ---------------- CSR build ----------------

__global__ void k_zero_i32(int* __restrict__ p, int n){
  int i = blockIdx.x * blockDim.x + threadIdx.x;
  if (i < n) p[i] = 0;
}

__global__ __launch_bounds__(256)
void k_rank(const int* __restrict__ erow, int* __restrict__ cnt, int* __restrict__ pos){
  const int t = blockIdx.x * 256 + threadIdx.x;
  #pragma unroll
  for (int k = 0; k < 8; ++k){
    const int e = t + k * ESLICE;
    if (e < NE){
      const int r = erow[e];
      pos[e] = atomicAdd(&cnt[r], 1);
    }
  }
}

__global__ __launch_bounds__(256)
void k_scan1(const int* __restrict__ cnt, int* __restrict__ rs, int* __restrict__ part, int n){
  const int t = threadIdx.x, b = blockIdx.x;
  const int i = b * 256 + t;
  int v = (i < n) ? cnt[i] : 0;
  const int lane = t & 63, w = t >> 6;
  int s = v;
  #pragma unroll
  for (int d = 1; d < 64; d <<= 1){ int u = __shfl_up(s, d); if (lane >= d) s += u; }
  __shared__ int wsum[4];
  if (lane == 63) wsum[w] = s;
  __syncthreads();
  int add = 0;
  #pragma unroll
  for (int k = 0; k < 4; ++k) if (k < w) add += wsum[k];
  s += add;
  if (i < n) rs[i + 1] = s;
  if (t == 255) part[b] = s;
}

__global__ __launch_bounds__(256)
void k_scan2(int* __restrict__ part, int nb){
  const int t = threadIdx.x;
  int v = (t < nb) ? part[t] : 0;
  const int lane = t & 63, w = t >> 6;
  int s = v;
  #pragma unroll
  for (int d = 1; d < 64; d <<= 1){ int u = __shfl_up(s, d); if (lane >= d) s += u; }
  __shared__ int wsum[4];
  if (lane == 63) wsum[w] = s;
  __syncthreads();
  int add = 0;
  #pragma unroll
  for (int k = 0; k < 4; ++k) if (k < w) add += wsum[k];
  s += add;
  if (t < nb) part[t] = s - v;
}

__global__ __launch_bounds__(256)
void k_scan3(int* __restrict__ rs, const int* __restrict__ part, int n){
  const int i = blockIdx.x * 256 + threadIdx.x;
  if (i < n) rs[i + 1] += part[blockIdx.x];
  if (i == 0) rs[0] = 0;
}

__global__ __launch_bounds__(256)
void k_scatter2(const int* __restrict__ erow, const int* __restrict__ ecol,
                const float* __restrict__ evalv, const int* __restrict__ rs,
                const int* __restrict__ pos, int2* __restrict__ out){
  const int t = blockIdx.x * 256 + threadIdx.x;
  #pragma unroll
  for (int k = 0; k < 8; ++k){
    const int e = t + k * ESLICE;
    if (e < NE){
      const int r = erow[e];
      const int p = rs[r] + pos[e];
      out[p] = make_int2(ecol[e], __float_as_int(evalv[e]));
    }
  }
}

// ---------------- fp32 -> bf16 conversions ----------------

__global__ __launch_bounds__(256)
void conv_bf16(const float* __restrict__ src, __bf16* __restrict__ dst,
               int M, int K, int Kp){
  const int q = blockIdx.x * 256 + threadIdx.x;
  const int perRow = Kp >> 2;
  const int r = q / perRow;
  const int k = (q - r * perRow) << 2;
  float4 v = make_float4(0.f, 0.f, 0.f, 0.f);
  if (r < M && k < K) v = *(const float4*)(src + (size_t)r * K + k);   // K % 4 == 0
  bf16x4 o;
  o[0] = (__bf16)v.x; o[1] = (__bf16)v.y; o[2] = (__bf16)v.z; o[3] = (__bf16)v.w;
  *(bf16x4*)(dst + (size_t)r * Kp + k) = o;
}

// blocks 0..79: W1 [256][300] -> W1b [256][320]; blocks 80..111: W2 [128][256] -> W2b.
__global__ __launch_bounds__(256)
void conv_w(const float* __restrict__ W1, const float* __restrict__ W2,
            __bf16* __restrict__ W1b, __bf16* __restrict__ W2b){
  const int b = blockIdx.x;
  const float* src; __bf16* dst; int q, K, Kp;
  if (b < 80){ src = W1; dst = W1b; q = b * 256 + threadIdx.x; K = 300; Kp = 320; }
  else       { src = W2; dst = W2b; q = (b - 80) * 256 + threadIdx.x; K = 256; Kp = 256; }
  const int perRow = Kp >> 2;
  const int r = q / perRow;
  const int k = (q - r * perRow) << 2;
  float4 v = make_float4(0.f, 0.f, 0.f, 0.f);
  if (k < K) v = *(const float4*)(src + (size_t)r * K + k);
  bf16x4 o;
  o[0] = (__bf16)v.x; o[1] = (__bf16)v.y; o[2] = (__bf16)v.z; o[3] = (__bf16)v.w;
  *(bf16x4*)(dst + (size_t)r * Kp + k) = o;
}

// ---------------- bf16 MFMA GEMM: BM=128, BN=64, BK=64, 48KB LDS (3 blocks/CU) ----------------
// C[Mpad][N] bf16 = A[Mpad][ld] * B[N][ld]^T. 4 waves 2x2 (wave tile 64x32),
// mfma 16x16x32, global_load_lds staging, both-sides XOR swizzle.
// XCD-aware block map: L = blockIdx.x; bm-tile = (L&7) + 8*(L>>(3+LGN));
// bn-tile = (L>>3)&(2^LGN-1). Same-bm tiles share XCD (L%8) -> A L2-reuse.

template<int KT, int LGN>
__global__ __launch_bounds__(256)
void gemm_bf16(const __bf16* __restrict__ A, const __bf16* __restrict__ B,
               __bf16* __restrict__ C, int ld, int N){
  __shared__ char ldsbuf[49152];                 // 2 x (16KB A + 8KB B); epi reuses 34.8KB
  const int tid = threadIdx.x;
  const int lane = tid & 63;
  const int L = blockIdx.x;
  const int bmt = (L & 7) + ((L >> (3 + LGN)) << 3);
  if (bmt >= 391) return;
  const int bm = bmt * 128;
  const int bn = ((L >> 3) & ((1 << LGN) - 1)) * 64;
  const int wr = (tid >> 7) & 1;
  const int wc = (tid >> 6) & 1;

  f32x4 acc[4][2];
  #pragma unroll
  for (int i = 0; i < 4; ++i)
    #pragma unroll
    for (int j = 0; j < 2; ++j) acc[i][j] = (f32x4){0.f, 0.f, 0.f, 0.f};

  auto stage = [&](int kt, int sel){
    char* lb = ldsbuf + sel * 24576;
    #pragma unroll
    for (int i = 0; i < 4; ++i){                 // A tile 16KB (128 rows x 128B)
      const int d = i * 4096 + tid * 16;
      const int row = d >> 7;
      const int colb = (d & 127) ^ ((row & 7) << 4);
      const __bf16* gp = A + (size_t)(bm + row) * ld + kt * 64 + (colb >> 1);
      gload16(gp, lb + i * 4096 + (tid & 192) * 16);
    }
    #pragma unroll
    for (int i = 0; i < 2; ++i){                 // B tile 8KB (64 rows x 128B)
      const int d = i * 4096 + tid * 16;
      const int row = d >> 7;
      const int colb = (d & 127) ^ ((row & 7) << 4);
      const __bf16* gp = B + (size_t)(bn + row) * ld + kt * 64 + (colb >> 1);
      gload16(gp, lb + 16384 + i * 4096 + (tid & 192) * 16);
    }
  };

  auto compute = [&](int sel){
    const char* lA = ldsbuf + sel * 24576;
    const char* lB = lA + 16384;
    #pragma unroll
    for (int c = 0; c < 2; ++c){
      bf16x8 av[4], bv[2];
      #pragma unroll
      for (int i = 0; i < 4; ++i){
        const int row = wr * 64 + i * 16 + (lane & 15);
        const int colb = (c * 64 + ((lane >> 4) << 4)) ^ ((row & 7) << 4);
        av[i] = *(const bf16x8*)(lA + row * 128 + colb);
      }
      #pragma unroll
      for (int j = 0; j < 2; ++j){
        const int row = wc * 32 + j * 16 + (lane & 15);
        const int colb = (c * 64 + ((lane >> 4) << 4)) ^ ((row & 7) << 4);
        bv[j] = *(const bf16x8*)(lB + row * 128 + colb);
      }
      #pragma unroll
      for (int i = 0; i < 4; ++i)
        #pragma unroll
        for (int j = 0; j < 2; ++j)
          acc[i][j] = __builtin_amdgcn_mfma_f32_16x16x32_bf16(av[i], bv[j], acc[i][j], 0, 0, 0);
    }
  };

  stage(0, 0);
  for (int kt = 0; kt < KT; ++kt){
    __syncthreads();
    if (kt + 1 < KT) stage(kt + 1, (kt + 1) & 1);
    compute(kt & 1);
  }

  // epilogue: acc -> LDS f32 [128][68] -> coalesced bf16x8 stores
  __syncthreads();
  float* lw = (float*)ldsbuf;
  #pragma unroll
  for (int i = 0; i < 4; ++i)
    #pragma unroll
    for (int j = 0; j < 2; ++j)
      #pragma unroll
      for (int r = 0; r < 4; ++r){
        const int row = wr * 64 + i * 16 + ((lane >> 4) << 2) + r;
        const int col = wc * 32 + j * 16 + (lane & 15);
        lw[row * 68 + col] = acc[i][j][r];
      }
  __syncthreads();
  #pragma unroll
  for (int p = 0; p < 4; ++p){
    const int row = p * 32 + (tid >> 3);
    const int col8 = (tid & 7) * 8;
    const float4 v0 = *(const float4*)&lw[row * 68 + col8];
    const float4 v1 = *(const float4*)&lw[row * 68 + col8 + 4];
    bf16x8 o;
    o[0] = (__bf16)v0.x; o[1] = (__bf16)v0.y; o[2] = (__bf16)v0.z; o[3] = (__bf16)v0.w;
    o[4] = (__bf16)v1.x; o[5] = (__bf16)v1.y; o[6] = (__bf16)v1.z; o[7] = (__bf16)v1.w;
    *(bf16x8*)(C + (size_t)(bm + row) * N + bn + col8) = o;
  }
}

// ---------------- SpMM (CSR, wave per row, 16-lane/edge quarters, x4 unroll) ----------------

__global__ __launch_bounds__(256)
void spmm_relu_half(const int2* __restrict__ ecv, const int* __restrict__ start,
                    const __bf16* __restrict__ H, const float* __restrict__ bias,
                    __bf16* __restrict__ out, int ch0){
  const int w = (blockIdx.x * 256 + threadIdx.x) >> 6;
  const int lane = threadIdx.x & 63;
  const int quar = lane >> 4, sl = lane & 15;
  if (w >= NN) return;
  const int s = start[w], e = start[w + 1];
  float a[8];
  #pragma unroll
  for (int k = 0; k < 8; ++k) a[k] = 0.f;
  for (int base = s; base < e; base += 64){
    int2 cv = make_int2(0, 0);
    if (base + lane < e) cv = ecv[base + lane];
    const int m = min(64, e - base);
    for (int j2 = 0; 16 * j2 < m; ++j2){
      int cc[4]; float vv[4];
      #pragma unroll
      for (int u = 0; u < 4; ++u){
        const int idx = 16 * j2 + quar + 4 * u;
        cc[u] = __shfl(cv.x, idx);
        vv[u] = __int_as_float(__shfl(cv.y, idx));
        if (idx >= m){ cc[u] = 0; vv[u] = 0.f; }
      }
      bf16x8 h[4];
      #pragma unroll
      for (int u = 0; u < 4; ++u)
        h[u] = *(const bf16x8*)(H + (size_t)cc[u] * 256 + ch0 + sl * 8);
      #pragma unroll
      for (int u = 0; u < 4; ++u)
        #pragma unroll
        for (int k = 0; k < 8; ++k) a[k] = fmaf(vv[u], (float)h[u][k], a[k]);
    }
  }
  #pragma unroll
  for (int k = 0; k < 8; ++k){
    a[k] += __shfl_xor(a[k], 32);
    a[k] += __shfl_xor(a[k], 16);
  }
  const float4 b0 = *(const float4*)(bias + ch0 + sl * 8);
  const float4 b1 = *(const float4*)(bias + ch0 + sl * 8 + 4);
  bf16x8 o;
  o[0] = (__bf16)fmaxf(a[0] + b0.x, 0.f);
  o[1] = (__bf16)fmaxf(a[1] + b0.y, 0.f);
  o[2] = (__bf16)fmaxf(a[2] + b0.z, 0.f);
  o[3] = (__bf16)fmaxf(a[3] + b0.w, 0.f);
  o[4] = (__bf16)fmaxf(a[4] + b1.x, 0.f);
  o[5] = (__bf16)fmaxf(a[5] + b1.y, 0.f);
  o[6] = (__bf16)fmaxf(a[6] + b1.z, 0.f);
  o[7] = (__bf16)fmaxf(a[7] + b1.w, 0.f);
  if (quar == 0) *(bf16x8*)(out + (size_t)w * 256 + ch0 + sl * 8) = o;
}

__global__ __launch_bounds__(256)
void spmm_bias_norm_b16(const int2* __restrict__ ecv, const int* __restrict__ start,
                        const __bf16* __restrict__ H, const float* __restrict__ bias,
                        float* __restrict__ out){
  const int w = (blockIdx.x * 256 + threadIdx.x) >> 6;
  const int lane = threadIdx.x & 63;
  const int quar = lane >> 4, sl = lane & 15;
  if (w >= NN) return;
  const int s = start[w], e = start[w + 1];
  float a[8];
  #pragma unroll
  for (int k = 0; k < 8; ++k) a[k] = 0.f;
  for (int base = s; base < e; base += 64){
    int2 cv = make_int2(0, 0);
    if (base + lane < e) cv = ecv[base + lane];
    const int m = min(64, e - base);
    for (int j2 = 0; 16 * j2 < m; ++j2){
      int cc[4]; float vv[4];
      #pragma unroll
      for (int u = 0; u < 4; ++u){
        const int idx = 16 * j2 + quar + 4 * u;
        cc[u] = __shfl(cv.x, idx);
        vv[u] = __int_as_float(__shfl(cv.y, idx));
        if (idx >= m){ cc[u] = 0; vv[u] = 0.f; }
      }
      bf16x8 h[4];
      #pragma unroll
      for (int u = 0; u < 4; ++u)
        h[u] = *(const bf16x8*)(H + (size_t)cc[u] * 128 + sl * 8);
      #pragma unroll
      for (int u = 0; u < 4; ++u)
        #pragma unroll
        for (int k = 0; k < 8; ++k) a[k] = fmaf(vv[u], (float)h[u][k], a[k]);
    }
  }
  #pragma unroll
  for (int k = 0; k < 8; ++k){
    a[k] += __shfl_xor(a[k], 32);
    a[k] += __shfl_xor(a[k], 16);
  }
  const float4 b0 = *(const float4*)(bias + sl * 8);
  const float4 b1 = *(const float4*)(bias + sl * 8 + 4);
  float f[8];
  f[0] = a[0] + b0.x; f[1] = a[1] + b0.y; f[2] = a[2] + b0.z; f[3] = a[3] + b0.w;
  f[4] = a[4] + b1.x; f[5] = a[5] + b1.y; f[6] = a[6] + b1.z; f[7] = a[7] + b1.w;
  float ss = 0.f;
  #pragma unroll
  for (int k = 0; k < 8; ++k) ss = fmaf(f[k], f[k], ss);
  #pragma unroll
  for (int m2 = 1; m2 < 16; m2 <<= 1) ss += __shfl_xor(ss, m2);
  const float inv = 1.f / fmaxf(sqrtf(ss), 1e-12f);
  if (quar == 0){
    float4 o0 = make_float4(f[0] * inv, f[1] * inv, f[2] * inv, f[3] * inv);
    float4 o1 = make_float4(f[4] * inv, f[5] * inv, f[6] * inv, f[7] * inv);
    *(float4*)(out + (size_t)w * 128 + sl * 8) = o0;
    *(float4*)(out + (size_t)w * 128 + sl * 8 + 4) = o1;
  }
}

// ---------------- launch ----------------
// ws layout (bytes):
//  xb  @ 0          [50048][320] bf16 = 32,030,720
//  W1b @ 32030720   [256][320]  bf16 =    163,840
//  W2b @ 32194560   [128][256]  bf16 =     65,536
//  h1  @ 32260096   [50048][256]bf16 = 25,624,576  (pos[800000] aliases head in CSR build)
//  h2  @ 57884672   [50048][256]bf16 = 25,624,576
//  h3  @ 83509248   [50048][128]bf16 = 12,812,288
//  ecv @ 96321536   800000 int2      =  6,400,000
//  rs  @ 102721536  50001 int        =    200,016
//  part@ 102921552  ~200 int
//  cur @ 102922368  50000 int        =    200,000   total ~103.1 MB

extern "C" void kernel_launch(void* const* d_in, const int* in_sizes, int n_in,
                              void* d_out, int out_size, void* d_ws, size_t ws_size,
                              hipStream_t stream){
  const float* x    = (const float*)d_in[0];
  const int*   erow = (const int*)d_in[1];
  const int*   ecol = (const int*)d_in[2];
  const float* evalv= (const float*)d_in[3];
  const float* W1   = (const float*)d_in[4];
  const float* b1   = (const float*)d_in[5];
  const float* W2   = (const float*)d_in[6];
  const float* b2   = (const float*)d_in[7];
  float* out = (float*)d_out;

  char* ws = (char*)d_ws;
  __bf16* xb  = (__bf16*)(ws);
  __bf16* W1b = (__bf16*)(ws + 32030720);
  __bf16* W2b = (__bf16*)(ws + 32194560);
  __bf16* h1  = (__bf16*)(ws + 32260096);
  __bf16* h2  = (__bf16*)(ws + 57884672);
  __bf16* h3  = (__bf16*)(ws + 83509248);
  int2*   ecv = (int2*)(ws + 96321536);
  int*    rs  = (int*)(ws + 102721536);
  int*    part= (int*)(ws + 102921552);
  int*    cur = (int*)(ws + 102922368);
  int*    pos = (int*)(ws + 32260096);   // aliases h1 head (dead until gemm1)

  // CSR build: rank(+hist) -> scan -> atomic-free scatter
  k_zero_i32<<<196, 256, 0, stream>>>(cur, NN);
  k_rank<<<391, 256, 0, stream>>>(erow, cur, pos);
  k_scan1<<<196, 256, 0, stream>>>(cur, rs, part, NN);
  k_scan2<<<1, 256, 0, stream>>>(part, 196);
  k_scan3<<<196, 256, 0, stream>>>(rs, part, NN);
  k_scatter2<<<391, 256, 0, stream>>>(erow, ecol, evalv, rs, pos, ecv);

  // conversions
  conv_bf16<<<15640, 256, 0, stream>>>(x, xb, NN, 300, 320);    // covers 50048 rows
  conv_w<<<112, 256, 0, stream>>>(W1, W2, W1b, W2b);

  // layer 1: h1 = bf16(xb @ W1b^T); h2 = bf16(relu(A*h1 + b1)) in two 128-ch halves
  gemm_bf16<5, 2><<<1568, 256, 0, stream>>>(xb, W1b, h1, 320, 256);
  spmm_relu_half<<<12500, 256, 0, stream>>>(ecv, rs, h1, b1, h2, 0);
  spmm_relu_half<<<12500, 256, 0, stream>>>(ecv, rs, h1, b1, h2, 128);

  // layer 2: h3 = bf16(h2 @ W2b^T); out = l2norm(A*h3 + b2)
  gemm_bf16<4, 1><<<784, 256, 0, stream>>>(h2, W2b, h3, 256, 128);
  spmm_bias_norm_b16<<<12500, 256, 0, stream>>>(ecv, rs, h3, b2, out);
}

// Round 11
// 190.625 us; speedup vs baseline: 1.1639x; 1.0356x over previous
//
#include <hip/hip_runtime.h>
#include <math.h>

#define NN 50000
#define NE 800000
#define ESLICE2 400128   // 1563 blocks * 256 threads; 2 slices cover NE

typedef __bf16 bf16x8 __attribute__((ext_vector_type(8)));
typedef __bf16 bf16x4 __attribute__((ext_vector_type(4)));
typedef float f32x4 __attribute__((ext_vector_type(4)));

__device__ __forceinline__ void gload16(const void* g, void* l){
  __builtin_amdgcn_global_load_lds((const __attribute__((address_space(1))) void*)g,
                                   (__attribute__((address_space(3))) void*)l, 16, 0, 0);
}

// ---------------- merged conversions + zero ----------------
// blocks [0,15640): x [50000][300] -> xb [50048][320] bf16
// blocks [15640,15752): W1 -> W1b (80), W2 -> W2b (32)
// blocks [15752,15948): zero cur[50000]

__global__ __launch_bounds__(256)
void conv_all(const float* __restrict__ x, const float* __restrict__ W1,
              const float* __restrict__ W2, __bf16* __restrict__ xb,
              __bf16* __restrict__ W1b, __bf16* __restrict__ W2b,
              int* __restrict__ cur){
  const int b = blockIdx.x;
  if (b >= 15752){
    const int i = (b - 15752) * 256 + threadIdx.x;
    if (i < NN) cur[i] = 0;
    return;
  }
  const float* src; __bf16* dst; int q, M, K, Kp;
  if (b < 15640){ src = x;  dst = xb;  q = b * 256 + threadIdx.x; M = NN;  K = 300; Kp = 320; }
  else if (b < 15720){ src = W1; dst = W1b; q = (b - 15640) * 256 + threadIdx.x; M = 256; K = 300; Kp = 320; }
  else { src = W2; dst = W2b; q = (b - 15720) * 256 + threadIdx.x; M = 128; K = 256; Kp = 256; }
  const int perRow = Kp >> 2;
  const int r = q / perRow;
  const int k = (q - r * perRow) << 2;
  float4 v = make_float4(0.f, 0.f, 0.f, 0.f);
  if (r < M && k < K) v = *(const float4*)(src + (size_t)r * K + k);   // K % 4 == 0
  bf16x4 o;
  o[0] = (__bf16)v.x; o[1] = (__bf16)v.y; o[2] = (__bf16)v.z; o[3] = (__bf16)v.w;
  *(bf16x4*)(dst + (size_t)r * Kp + k) = o;
}

// ---------------- CSR build ----------------

__global__ __launch_bounds__(256)
void k_rank(const int* __restrict__ erow, int* __restrict__ cnt, int* __restrict__ pos){
  const int t = blockIdx.x * 256 + threadIdx.x;
  #pragma unroll
  for (int k = 0; k < 2; ++k){
    const int e = t + k * ESLICE2;
    if (e < NE){
      const int r = erow[e];
      pos[e] = atomicAdd(&cnt[r], 1);
    }
  }
}

__global__ __launch_bounds__(256)
void k_scan1(const int* __restrict__ cnt, int* __restrict__ rs, int* __restrict__ part, int n){
  const int t = threadIdx.x, b = blockIdx.x;
  const int i = b * 256 + t;
  int v = (i < n) ? cnt[i] : 0;
  const int lane = t & 63, w = t >> 6;
  int s = v;
  #pragma unroll
  for (int d = 1; d < 64; d <<= 1){ int u = __shfl_up(s, d); if (lane >= d) s += u; }
  __shared__ int wsum[4];
  if (lane == 63) wsum[w] = s;
  __syncthreads();
  int add = 0;
  #pragma unroll
  for (int k = 0; k < 4; ++k) if (k < w) add += wsum[k];
  s += add;
  if (i < n) rs[i + 1] = s;
  if (t == 255) part[b] = s;
}

// block b: add prefix sum(part[0..b)) to rs; also rs[0]=0. (folds old scan2+scan3)
__global__ __launch_bounds__(256)
void k_scan3(int* __restrict__ rs, const int* __restrict__ part, int n){
  const int t = threadIdx.x, b = blockIdx.x;
  int v = (t < b) ? part[t] : 0;                 // b <= 195 < 256
  const int lane = t & 63, w = t >> 6;
  #pragma unroll
  for (int m = 32; m; m >>= 1) v += __shfl_xor(v, m);
  __shared__ int wsum[4];
  if (lane == 0) wsum[w] = v;
  __syncthreads();
  const int add = wsum[0] + wsum[1] + wsum[2] + wsum[3];
  const int i = b * 256 + t;
  if (i < n) rs[i + 1] += add;
  if (b == 0 && t == 0) rs[0] = 0;
}

__global__ __launch_bounds__(256)
void k_scatter2(const int* __restrict__ erow, const int* __restrict__ ecol,
                const float* __restrict__ evalv, const int* __restrict__ rs,
                const int* __restrict__ pos, int2* __restrict__ out){
  const int t = blockIdx.x * 256 + threadIdx.x;
  #pragma unroll
  for (int k = 0; k < 2; ++k){
    const int e = t + k * ESLICE2;
    if (e < NE){
      const int r = erow[e];
      const int p = rs[r] + pos[e];
      out[p] = make_int2(ecol[e], __float_as_int(evalv[e]));
    }
  }
}

// ---------------- bf16 MFMA GEMM: BM=128, BN=64, BK=64, 48KB LDS (3 blocks/CU) ----------------
// XCD-aware block map: same-bm tiles share XCD -> A L2-reuse.

template<int KT, int LGN>
__global__ __launch_bounds__(256)
void gemm_bf16(const __bf16* __restrict__ A, const __bf16* __restrict__ B,
               __bf16* __restrict__ C, int ld, int N){
  __shared__ char ldsbuf[49152];                 // 2 x (16KB A + 8KB B); epi reuses 34.8KB
  const int tid = threadIdx.x;
  const int lane = tid & 63;
  const int L = blockIdx.x;
  const int bmt = (L & 7) + ((L >> (3 + LGN)) << 3);
  if (bmt >= 391) return;
  const int bm = bmt * 128;
  const int bn = ((L >> 3) & ((1 << LGN) - 1)) * 64;
  const int wr = (tid >> 7) & 1;
  const int wc = (tid >> 6) & 1;

  f32x4 acc[4][2];
  #pragma unroll
  for (int i = 0; i < 4; ++i)
    #pragma unroll
    for (int j = 0; j < 2; ++j) acc[i][j] = (f32x4){0.f, 0.f, 0.f, 0.f};

  auto stage = [&](int kt, int sel){
    char* lb = ldsbuf + sel * 24576;
    #pragma unroll
    for (int i = 0; i < 4; ++i){                 // A tile 16KB (128 rows x 128B)
      const int d = i * 4096 + tid * 16;
      const int row = d >> 7;
      const int colb = (d & 127) ^ ((row & 7) << 4);
      const __bf16* gp = A + (size_t)(bm + row) * ld + kt * 64 + (colb >> 1);
      gload16(gp, lb + i * 4096 + (tid & 192) * 16);
    }
    #pragma unroll
    for (int i = 0; i < 2; ++i){                 // B tile 8KB (64 rows x 128B)
      const int d = i * 4096 + tid * 16;
      const int row = d >> 7;
      const int colb = (d & 127) ^ ((row & 7) << 4);
      const __bf16* gp = B + (size_t)(bn + row) * ld + kt * 64 + (colb >> 1);
      gload16(gp, lb + 16384 + i * 4096 + (tid & 192) * 16);
    }
  };

  auto compute = [&](int sel){
    const char* lA = ldsbuf + sel * 24576;
    const char* lB = lA + 16384;
    #pragma unroll
    for (int c = 0; c < 2; ++c){
      bf16x8 av[4], bv[2];
      #pragma unroll
      for (int i = 0; i < 4; ++i){
        const int row = wr * 64 + i * 16 + (lane & 15);
        const int colb = (c * 64 + ((lane >> 4) << 4)) ^ ((row & 7) << 4);
        av[i] = *(const bf16x8*)(lA + row * 128 + colb);
      }
      #pragma unroll
      for (int j = 0; j < 2; ++j){
        const int row = wc * 32 + j * 16 + (lane & 15);
        const int colb = (c * 64 + ((lane >> 4) << 4)) ^ ((row & 7) << 4);
        bv[j] = *(const bf16x8*)(lB + row * 128 + colb);
      }
      #pragma unroll
      for (int i = 0; i < 4; ++i)
        #pragma unroll
        for (int j = 0; j < 2; ++j)
          acc[i][j] = __builtin_amdgcn_mfma_f32_16x16x32_bf16(av[i], bv[j], acc[i][j], 0, 0, 0);
    }
  };

  stage(0, 0);
  for (int kt = 0; kt < KT; ++kt){
    __syncthreads();
    if (kt + 1 < KT) stage(kt + 1, (kt + 1) & 1);
    compute(kt & 1);
  }

  // epilogue: acc -> LDS f32 [128][68] -> coalesced bf16x8 stores
  __syncthreads();
  float* lw = (float*)ldsbuf;
  #pragma unroll
  for (int i = 0; i < 4; ++i)
    #pragma unroll
    for (int j = 0; j < 2; ++j)
      #pragma unroll
      for (int r = 0; r < 4; ++r){
        const int row = wr * 64 + i * 16 + ((lane >> 4) << 2) + r;
        const int col = wc * 32 + j * 16 + (lane & 15);
        lw[row * 68 + col] = acc[i][j][r];
      }
  __syncthreads();
  #pragma unroll
  for (int p = 0; p < 4; ++p){
    const int row = p * 32 + (tid >> 3);
    const int col8 = (tid & 7) * 8;
    const float4 v0 = *(const float4*)&lw[row * 68 + col8];
    const float4 v1 = *(const float4*)&lw[row * 68 + col8 + 4];
    bf16x8 o;
    o[0] = (__bf16)v0.x; o[1] = (__bf16)v0.y; o[2] = (__bf16)v0.z; o[3] = (__bf16)v0.w;
    o[4] = (__bf16)v1.x; o[5] = (__bf16)v1.y; o[6] = (__bf16)v1.z; o[7] = (__bf16)v1.w;
    *(bf16x8*)(C + (size_t)(bm + row) * N + bn + col8) = o;
  }
}

// ---------------- SpMM (CSR, wave per row, 16-lane/edge quarters, x4 unroll) ----------------

__global__ __launch_bounds__(256)
void spmm_relu_half(const int2* __restrict__ ecv, const int* __restrict__ start,
                    const __bf16* __restrict__ H, const float* __restrict__ bias,
                    __bf16* __restrict__ out, int ch0){
  const int w = (blockIdx.x * 256 + threadIdx.x) >> 6;
  const int lane = threadIdx.x & 63;
  const int quar = lane >> 4, sl = lane & 15;
  if (w >= NN) return;
  const int s = start[w], e = start[w + 1];
  float a[8];
  #pragma unroll
  for (int k = 0; k < 8; ++k) a[k] = 0.f;
  for (int base = s; base < e; base += 64){
    int2 cv = make_int2(0, 0);
    if (base + lane < e) cv = ecv[base + lane];
    const int m = min(64, e - base);
    for (int j2 = 0; 16 * j2 < m; ++j2){
      int cc[4]; float vv[4];
      #pragma unroll
      for (int u = 0; u < 4; ++u){
        const int idx = 16 * j2 + quar + 4 * u;
        cc[u] = __shfl(cv.x, idx);
        vv[u] = __int_as_float(__shfl(cv.y, idx));
        if (idx >= m){ cc[u] = 0; vv[u] = 0.f; }
      }
      bf16x8 h[4];
      #pragma unroll
      for (int u = 0; u < 4; ++u)
        h[u] = *(const bf16x8*)(H + (size_t)cc[u] * 256 + ch0 + sl * 8);
      #pragma unroll
      for (int u = 0; u < 4; ++u)
        #pragma unroll
        for (int k = 0; k < 8; ++k) a[k] = fmaf(vv[u], (float)h[u][k], a[k]);
    }
  }
  #pragma unroll
  for (int k = 0; k < 8; ++k){
    a[k] += __shfl_xor(a[k], 32);
    a[k] += __shfl_xor(a[k], 16);
  }
  const float4 b0 = *(const float4*)(bias + ch0 + sl * 8);
  const float4 b1 = *(const float4*)(bias + ch0 + sl * 8 + 4);
  bf16x8 o;
  o[0] = (__bf16)fmaxf(a[0] + b0.x, 0.f);
  o[1] = (__bf16)fmaxf(a[1] + b0.y, 0.f);
  o[2] = (__bf16)fmaxf(a[2] + b0.z, 0.f);
  o[3] = (__bf16)fmaxf(a[3] + b0.w, 0.f);
  o[4] = (__bf16)fmaxf(a[4] + b1.x, 0.f);
  o[5] = (__bf16)fmaxf(a[5] + b1.y, 0.f);
  o[6] = (__bf16)fmaxf(a[6] + b1.z, 0.f);
  o[7] = (__bf16)fmaxf(a[7] + b1.w, 0.f);
  if (quar == 0) *(bf16x8*)(out + (size_t)w * 256 + ch0 + sl * 8) = o;
}

__global__ __launch_bounds__(256)
void spmm_bias_norm_b16(const int2* __restrict__ ecv, const int* __restrict__ start,
                        const __bf16* __restrict__ H, const float* __restrict__ bias,
                        float* __restrict__ out){
  const int w = (blockIdx.x * 256 + threadIdx.x) >> 6;
  const int lane = threadIdx.x & 63;
  const int quar = lane >> 4, sl = lane & 15;
  if (w >= NN) return;
  const int s = start[w], e = start[w + 1];
  float a[8];
  #pragma unroll
  for (int k = 0; k < 8; ++k) a[k] = 0.f;
  for (int base = s; base < e; base += 64){
    int2 cv = make_int2(0, 0);
    if (base + lane < e) cv = ecv[base + lane];
    const int m = min(64, e - base);
    for (int j2 = 0; 16 * j2 < m; ++j2){
      int cc[4]; float vv[4];
      #pragma unroll
      for (int u = 0; u < 4; ++u){
        const int idx = 16 * j2 + quar + 4 * u;
        cc[u] = __shfl(cv.x, idx);
        vv[u] = __int_as_float(__shfl(cv.y, idx));
        if (idx >= m){ cc[u] = 0; vv[u] = 0.f; }
      }
      bf16x8 h[4];
      #pragma unroll
      for (int u = 0; u < 4; ++u)
        h[u] = *(const bf16x8*)(H + (size_t)cc[u] * 128 + sl * 8);
      #pragma unroll
      for (int u = 0; u < 4; ++u)
        #pragma unroll
        for (int k = 0; k < 8; ++k) a[k] = fmaf(vv[u], (float)h[u][k], a[k]);
    }
  }
  #pragma unroll
  for (int k = 0; k < 8; ++k){
    a[k] += __shfl_xor(a[k], 32);
    a[k] += __shfl_xor(a[k], 16);
  }
  const float4 b0 = *(const float4*)(bias + sl * 8);
  const float4 b1 = *(const float4*)(bias + sl * 8 + 4);
  float f[8];
  f[0] = a[0] + b0.x; f[1] = a[1] + b0.y; f[2] = a[2] + b0.z; f[3] = a[3] + b0.w;
  f[4] = a[4] + b1.x; f[5] = a[5] + b1.y; f[6] = a[6] + b1.z; f[7] = a[7] + b1.w;
  float ss = 0.f;
  #pragma unroll
  for (int k = 0; k < 8; ++k) ss = fmaf(f[k], f[k], ss);
  #pragma unroll
  for (int m2 = 1; m2 < 16; m2 <<= 1) ss += __shfl_xor(ss, m2);
  const float inv = 1.f / fmaxf(sqrtf(ss), 1e-12f);
  if (quar == 0){
    float4 o0 = make_float4(f[0] * inv, f[1] * inv, f[2] * inv, f[3] * inv);
    float4 o1 = make_float4(f[4] * inv, f[5] * inv, f[6] * inv, f[7] * inv);
    *(float4*)(out + (size_t)w * 128 + sl * 8) = o0;
    *(float4*)(out + (size_t)w * 128 + sl * 8 + 4) = o1;
  }
}

// ---------------- launch ----------------
// ws layout (bytes):
//  xb  @ 0          [50048][320] bf16 = 32,030,720
//  W1b @ 32030720   [256][320]  bf16 =    163,840
//  W2b @ 32194560   [128][256]  bf16 =     65,536
//  h1  @ 32260096   [50048][256]bf16 = 25,624,576  (pos[800000] aliases head in CSR build)
//  h2  @ 57884672   [50048][256]bf16 = 25,624,576
//  h3  @ 83509248   [50048][128]bf16 = 12,812,288
//  ecv @ 96321536   800000 int2      =  6,400,000
//  rs  @ 102721536  50001 int        =    200,016
//  part@ 102921552  ~200 int
//  cur @ 102922368  50000 int        =    200,000   total ~103.1 MB

extern "C" void kernel_launch(void* const* d_in, const int* in_sizes, int n_in,
                              void* d_out, int out_size, void* d_ws, size_t ws_size,
                              hipStream_t stream){
  const float* x    = (const float*)d_in[0];
  const int*   erow = (const int*)d_in[1];
  const int*   ecol = (const int*)d_in[2];
  const float* evalv= (const float*)d_in[3];
  const float* W1   = (const float*)d_in[4];
  const float* b1   = (const float*)d_in[5];
  const float* W2   = (const float*)d_in[6];
  const float* b2   = (const float*)d_in[7];
  float* out = (float*)d_out;

  char* ws = (char*)d_ws;
  __bf16* xb  = (__bf16*)(ws);
  __bf16* W1b = (__bf16*)(ws + 32030720);
  __bf16* W2b = (__bf16*)(ws + 32194560);
  __bf16* h1  = (__bf16*)(ws + 32260096);
  __bf16* h2  = (__bf16*)(ws + 57884672);
  __bf16* h3  = (__bf16*)(ws + 83509248);
  int2*   ecv = (int2*)(ws + 96321536);
  int*    rs  = (int*)(ws + 102721536);
  int*    part= (int*)(ws + 102921552);
  int*    cur = (int*)(ws + 102922368);
  int*    pos = (int*)(ws + 32260096);   // aliases h1 head (dead until gemm1)

  // conversions + zero(cur), one dispatch
  conv_all<<<15948, 256, 0, stream>>>(x, W1, W2, xb, W1b, W2b, cur);

  // CSR build: rank(+hist) -> scan1 -> scan3(inline part-prefix) -> atomic-free scatter
  k_rank<<<1563, 256, 0, stream>>>(erow, cur, pos);
  k_scan1<<<196, 256, 0, stream>>>(cur, rs, part, NN);
  k_scan3<<<196, 256, 0, stream>>>(rs, part, NN);
  k_scatter2<<<1563, 256, 0, stream>>>(erow, ecol, evalv, rs, pos, ecv);

  // layer 1: h1 = bf16(xb @ W1b^T); h2 = bf16(relu(A*h1 + b1)) in two 128-ch halves
  gemm_bf16<5, 2><<<1568, 256, 0, stream>>>(xb, W1b, h1, 320, 256);
  spmm_relu_half<<<12500, 256, 0, stream>>>(ecv, rs, h1, b1, h2, 0);
  spmm_relu_half<<<12500, 256, 0, stream>>>(ecv, rs, h1, b1, h2, 128);

  // layer 2: h3 = bf16(h2 @ W2b^T); out = l2norm(A*h3 + b2)
  gemm_bf16<4, 1><<<784, 256, 0, stream>>>(h2, W2b, h3, 256, 128);
  spmm_bias_norm_b16<<<12500, 256, 0, stream>>>(ecv, rs, h3, b2, out);
}

// Round 13
// 181.853 us; speedup vs baseline: 1.2200x; 1.0482x over previous
//
#include <hip/hip_runtime.h>
#include <math.h>

#define NN 50000
#define NE 800000
#define ESLICE2 400128   // 1563 blocks * 256 threads; 2 slices cover NE

typedef __bf16 bf16x8 __attribute__((ext_vector_type(8)));
typedef __bf16 bf16x4 __attribute__((ext_vector_type(4)));
typedef float f32x4 __attribute__((ext_vector_type(4)));

__device__ __forceinline__ void gload16(const void* g, void* l){
  __builtin_amdgcn_global_load_lds((const __attribute__((address_space(1))) void*)g,
                                   (__attribute__((address_space(3))) void*)l, 16, 0, 0);
}

// ---------------- zero cur ----------------

__global__ __launch_bounds__(256)
void k_zero(int* __restrict__ p){
  const int i = blockIdx.x * 256 + threadIdx.x;
  if (i < NN) p[i] = 0;
}

// ---------------- merged rank + conversions ----------------
// blocks [0,1563): rank (atomic hist + per-edge pos), overlapped with:
// blocks [1563,17203): x -> xb; [17203,17283): W1 -> W1b; [17283,17315): W2 -> W2b

__global__ __launch_bounds__(256)
void rank_conv(const int* __restrict__ erow, int* __restrict__ cnt, int* __restrict__ pos,
               const float* __restrict__ x, const float* __restrict__ W1,
               const float* __restrict__ W2, __bf16* __restrict__ xb,
               __bf16* __restrict__ W1b, __bf16* __restrict__ W2b){
  const int b = blockIdx.x;
  if (b < 1563){
    const int t = b * 256 + threadIdx.x;
    #pragma unroll
    for (int k = 0; k < 2; ++k){
      const int e = t + k * ESLICE2;
      if (e < NE){
        const int r = erow[e];
        pos[e] = atomicAdd(&cnt[r], 1);
      }
    }
    return;
  }
  const int cb = b - 1563;
  const float* src; __bf16* dst; int q, M, K, Kp;
  if (cb < 15640){ src = x;  dst = xb;  q = cb * 256 + threadIdx.x; M = NN;  K = 300; Kp = 320; }
  else if (cb < 15720){ src = W1; dst = W1b; q = (cb - 15640) * 256 + threadIdx.x; M = 256; K = 300; Kp = 320; }
  else { src = W2; dst = W2b; q = (cb - 15720) * 256 + threadIdx.x; M = 128; K = 256; Kp = 256; }
  const int perRow = Kp >> 2;
  const int r = q / perRow;
  const int k = (q - r * perRow) << 2;
  float4 v = make_float4(0.f, 0.f, 0.f, 0.f);
  if (r < M && k < K) v = *(const float4*)(src + (size_t)r * K + k);   // K % 4 == 0
  bf16x4 o;
  o[0] = (__bf16)v.x; o[1] = (__bf16)v.y; o[2] = (__bf16)v.z; o[3] = (__bf16)v.w;
  *(bf16x4*)(dst + (size_t)r * Kp + k) = o;
}

// ---------------- scans ----------------

__global__ __launch_bounds__(256)
void k_scan1(const int* __restrict__ cnt, int* __restrict__ rs, int* __restrict__ part, int n){
  const int t = threadIdx.x, b = blockIdx.x;
  const int i = b * 256 + t;
  int v = (i < n) ? cnt[i] : 0;
  const int lane = t & 63, w = t >> 6;
  int s = v;
  #pragma unroll
  for (int d = 1; d < 64; d <<= 1){ int u = __shfl_up(s, d); if (lane >= d) s += u; }
  __shared__ int wsum[4];
  if (lane == 63) wsum[w] = s;
  __syncthreads();
  int add = 0;
  #pragma unroll
  for (int k = 0; k < 4; ++k) if (k < w) add += wsum[k];
  s += add;
  if (i < n) rs[i + 1] = s;
  if (t == 255) part[b] = s;
}

// block b: add prefix sum(part[0..b)) to rs; also rs[0]=0.
__global__ __launch_bounds__(256)
void k_scan3(int* __restrict__ rs, const int* __restrict__ part, int n){
  const int t = threadIdx.x, b = blockIdx.x;
  int v = (t < b) ? part[t] : 0;                 // b <= 195 < 256
  const int lane = t & 63, w = t >> 6;
  #pragma unroll
  for (int m = 32; m; m >>= 1) v += __shfl_xor(v, m);
  __shared__ int wsum[4];
  if (lane == 0) wsum[w] = v;
  __syncthreads();
  const int add = wsum[0] + wsum[1] + wsum[2] + wsum[3];
  const int i = b * 256 + t;
  if (i < n) rs[i + 1] += add;
  if (b == 0 && t == 0) rs[0] = 0;
}

// ---------------- merged scatter + GEMM1 ----------------
// blocks [0,1563): atomic-free edge scatter into ecv
// blocks [1563,3131): bf16 MFMA gemm tiles (BM=128, BN=64, BK=64, XCD-aware map)

template<int KT, int LGN>
__global__ __launch_bounds__(256)
void scat_gemm(const int* __restrict__ erow, const int* __restrict__ ecol,
               const float* __restrict__ evalv, const int* __restrict__ rs,
               const int* __restrict__ pos, int2* __restrict__ ecv,
               const __bf16* __restrict__ A, const __bf16* __restrict__ B,
               __bf16* __restrict__ C, int ld, int N){
  __shared__ char ldsbuf[49152];
  const int tid = threadIdx.x;
  if (blockIdx.x < 1563){
    const int t = blockIdx.x * 256 + tid;
    #pragma unroll
    for (int k = 0; k < 2; ++k){
      const int e = t + k * ESLICE2;
      if (e < NE){
        const int r = erow[e];
        const int p = rs[r] + pos[e];
        ecv[p] = make_int2(ecol[e], __float_as_int(evalv[e]));
      }
    }
    return;
  }
  const int lane = tid & 63;
  const int L = blockIdx.x - 1563;
  const int bmt = (L & 7) + ((L >> (3 + LGN)) << 3);
  if (bmt >= 391) return;
  const int bm = bmt * 128;
  const int bn = ((L >> 3) & ((1 << LGN) - 1)) * 64;
  const int wr = (tid >> 7) & 1;
  const int wc = (tid >> 6) & 1;

  f32x4 acc[4][2];
  #pragma unroll
  for (int i = 0; i < 4; ++i)
    #pragma unroll
    for (int j = 0; j < 2; ++j) acc[i][j] = (f32x4){0.f, 0.f, 0.f, 0.f};

  auto stage = [&](int kt, int sel){
    char* lb = ldsbuf + sel * 24576;
    #pragma unroll
    for (int i = 0; i < 4; ++i){
      const int d = i * 4096 + tid * 16;
      const int row = d >> 7;
      const int colb = (d & 127) ^ ((row & 7) << 4);
      const __bf16* gp = A + (size_t)(bm + row) * ld + kt * 64 + (colb >> 1);
      gload16(gp, lb + i * 4096 + (tid & 192) * 16);
    }
    #pragma unroll
    for (int i = 0; i < 2; ++i){
      const int d = i * 4096 + tid * 16;
      const int row = d >> 7;
      const int colb = (d & 127) ^ ((row & 7) << 4);
      const __bf16* gp = B + (size_t)(bn + row) * ld + kt * 64 + (colb >> 1);
      gload16(gp, lb + 16384 + i * 4096 + (tid & 192) * 16);
    }
  };

  auto compute = [&](int sel){
    const char* lA = ldsbuf + sel * 24576;
    const char* lB = lA + 16384;
    #pragma unroll
    for (int c = 0; c < 2; ++c){
      bf16x8 av[4], bv[2];
      #pragma unroll
      for (int i = 0; i < 4; ++i){
        const int row = wr * 64 + i * 16 + (lane & 15);
        const int colb = (c * 64 + ((lane >> 4) << 4)) ^ ((row & 7) << 4);
        av[i] = *(const bf16x8*)(lA + row * 128 + colb);
      }
      #pragma unroll
      for (int j = 0; j < 2; ++j){
        const int row = wc * 32 + j * 16 + (lane & 15);
        const int colb = (c * 64 + ((lane >> 4) << 4)) ^ ((row & 7) << 4);
        bv[j] = *(const bf16x8*)(lB + row * 128 + colb);
      }
      #pragma unroll
      for (int i = 0; i < 4; ++i)
        #pragma unroll
        for (int j = 0; j < 2; ++j)
          acc[i][j] = __builtin_amdgcn_mfma_f32_16x16x32_bf16(av[i], bv[j], acc[i][j], 0, 0, 0);
    }
  };

  stage(0, 0);
  for (int kt = 0; kt < KT; ++kt){
    __syncthreads();
    if (kt + 1 < KT) stage(kt + 1, (kt + 1) & 1);
    compute(kt & 1);
  }

  __syncthreads();
  float* lw = (float*)ldsbuf;
  #pragma unroll
  for (int i = 0; i < 4; ++i)
    #pragma unroll
    for (int j = 0; j < 2; ++j)
      #pragma unroll
      for (int r = 0; r < 4; ++r){
        const int row = wr * 64 + i * 16 + ((lane >> 4) << 2) + r;
        const int col = wc * 32 + j * 16 + (lane & 15);
        lw[row * 68 + col] = acc[i][j][r];
      }
  __syncthreads();
  #pragma unroll
  for (int p = 0; p < 4; ++p){
    const int row = p * 32 + (tid >> 3);
    const int col8 = (tid & 7) * 8;
    const float4 v0 = *(const float4*)&lw[row * 68 + col8];
    const float4 v1 = *(const float4*)&lw[row * 68 + col8 + 4];
    bf16x8 o;
    o[0] = (__bf16)v0.x; o[1] = (__bf16)v0.y; o[2] = (__bf16)v0.z; o[3] = (__bf16)v0.w;
    o[4] = (__bf16)v1.x; o[5] = (__bf16)v1.y; o[6] = (__bf16)v1.z; o[7] = (__bf16)v1.w;
    *(bf16x8*)(C + (size_t)(bm + row) * N + bn + col8) = o;
  }
}

// ---------------- plain GEMM (layer 2) ----------------

template<int KT, int LGN>
__global__ __launch_bounds__(256)
void gemm_bf16(const __bf16* __restrict__ A, const __bf16* __restrict__ B,
               __bf16* __restrict__ C, int ld, int N){
  __shared__ char ldsbuf[49152];
  const int tid = threadIdx.x;
  const int lane = tid & 63;
  const int L = blockIdx.x;
  const int bmt = (L & 7) + ((L >> (3 + LGN)) << 3);
  if (bmt >= 391) return;
  const int bm = bmt * 128;
  const int bn = ((L >> 3) & ((1 << LGN) - 1)) * 64;
  const int wr = (tid >> 7) & 1;
  const int wc = (tid >> 6) & 1;

  f32x4 acc[4][2];
  #pragma unroll
  for (int i = 0; i < 4; ++i)
    #pragma unroll
    for (int j = 0; j < 2; ++j) acc[i][j] = (f32x4){0.f, 0.f, 0.f, 0.f};

  auto stage = [&](int kt, int sel){
    char* lb = ldsbuf + sel * 24576;
    #pragma unroll
    for (int i = 0; i < 4; ++i){
      const int d = i * 4096 + tid * 16;
      const int row = d >> 7;
      const int colb = (d & 127) ^ ((row & 7) << 4);
      const __bf16* gp = A + (size_t)(bm + row) * ld + kt * 64 + (colb >> 1);
      gload16(gp, lb + i * 4096 + (tid & 192) * 16);
    }
    #pragma unroll
    for (int i = 0; i < 2; ++i){
      const int d = i * 4096 + tid * 16;
      const int row = d >> 7;
      const int colb = (d & 127) ^ ((row & 7) << 4);
      const __bf16* gp = B + (size_t)(bn + row) * ld + kt * 64 + (colb >> 1);
      gload16(gp, lb + 16384 + i * 4096 + (tid & 192) * 16);
    }
  };

  auto compute = [&](int sel){
    const char* lA = ldsbuf + sel * 24576;
    const char* lB = lA + 16384;
    #pragma unroll
    for (int c = 0; c < 2; ++c){
      bf16x8 av[4], bv[2];
      #pragma unroll
      for (int i = 0; i < 4; ++i){
        const int row = wr * 64 + i * 16 + (lane & 15);
        const int colb = (c * 64 + ((lane >> 4) << 4)) ^ ((row & 7) << 4);
        av[i] = *(const bf16x8*)(lA + row * 128 + colb);
      }
      #pragma unroll
      for (int j = 0; j < 2; ++j){
        const int row = wc * 32 + j * 16 + (lane & 15);
        const int colb = (c * 64 + ((lane >> 4) << 4)) ^ ((row & 7) << 4);
        bv[j] = *(const bf16x8*)(lB + row * 128 + colb);
      }
      #pragma unroll
      for (int i = 0; i < 4; ++i)
        #pragma unroll
        for (int j = 0; j < 2; ++j)
          acc[i][j] = __builtin_amdgcn_mfma_f32_16x16x32_bf16(av[i], bv[j], acc[i][j], 0, 0, 0);
    }
  };

  stage(0, 0);
  for (int kt = 0; kt < KT; ++kt){
    __syncthreads();
    if (kt + 1 < KT) stage(kt + 1, (kt + 1) & 1);
    compute(kt & 1);
  }

  __syncthreads();
  float* lw = (float*)ldsbuf;
  #pragma unroll
  for (int i = 0; i < 4; ++i)
    #pragma unroll
    for (int j = 0; j < 2; ++j)
      #pragma unroll
      for (int r = 0; r < 4; ++r){
        const int row = wr * 64 + i * 16 + ((lane >> 4) << 2) + r;
        const int col = wc * 32 + j * 16 + (lane & 15);
        lw[row * 68 + col] = acc[i][j][r];
      }
  __syncthreads();
  #pragma unroll
  for (int p = 0; p < 4; ++p){
    const int row = p * 32 + (tid >> 3);
    const int col8 = (tid & 7) * 8;
    const float4 v0 = *(const float4*)&lw[row * 68 + col8];
    const float4 v1 = *(const float4*)&lw[row * 68 + col8 + 4];
    bf16x8 o;
    o[0] = (__bf16)v0.x; o[1] = (__bf16)v0.y; o[2] = (__bf16)v0.z; o[3] = (__bf16)v0.w;
    o[4] = (__bf16)v1.x; o[5] = (__bf16)v1.y; o[6] = (__bf16)v1.z; o[7] = (__bf16)v1.w;
    *(bf16x8*)(C + (size_t)(bm + row) * N + bn + col8) = o;
  }
}

// ---------------- SpMM (CSR, wave per row, 16-lane/edge quarters, x4 unroll) ----------------
// Both 128-ch halves in one dispatch: blocks [0,12500) ch0=0, [12500,25000) ch0=128.

__global__ __launch_bounds__(256)
void spmm_relu_b16(const int2* __restrict__ ecv, const int* __restrict__ start,
                   const __bf16* __restrict__ H, const float* __restrict__ bias,
                   __bf16* __restrict__ out){
  const int half = (blockIdx.x >= 12500) ? 1 : 0;
  const int bb = blockIdx.x - half * 12500;
  const int ch0 = half * 128;
  const int w = (bb * 256 + threadIdx.x) >> 6;
  const int lane = threadIdx.x & 63;
  const int quar = lane >> 4, sl = lane & 15;
  if (w >= NN) return;
  const int s = start[w], e = start[w + 1];
  float a[8];
  #pragma unroll
  for (int k = 0; k < 8; ++k) a[k] = 0.f;
  for (int base = s; base < e; base += 64){
    int2 cv = make_int2(0, 0);
    if (base + lane < e) cv = ecv[base + lane];
    const int m = min(64, e - base);
    for (int j2 = 0; 16 * j2 < m; ++j2){
      int cc[4]; float vv[4];
      #pragma unroll
      for (int u = 0; u < 4; ++u){
        const int idx = 16 * j2 + quar + 4 * u;
        cc[u] = __shfl(cv.x, idx);
        vv[u] = __int_as_float(__shfl(cv.y, idx));
        if (idx >= m){ cc[u] = 0; vv[u] = 0.f; }
      }
      bf16x8 h[4];
      #pragma unroll
      for (int u = 0; u < 4; ++u)
        h[u] = *(const bf16x8*)(H + (size_t)cc[u] * 256 + ch0 + sl * 8);
      #pragma unroll
      for (int u = 0; u < 4; ++u)
        #pragma unroll
        for (int k = 0; k < 8; ++k) a[k] = fmaf(vv[u], (float)h[u][k], a[k]);
    }
  }
  #pragma unroll
  for (int k = 0; k < 8; ++k){
    a[k] += __shfl_xor(a[k], 32);
    a[k] += __shfl_xor(a[k], 16);
  }
  const float4 b0 = *(const float4*)(bias + ch0 + sl * 8);
  const float4 b1 = *(const float4*)(bias + ch0 + sl * 8 + 4);
  bf16x8 o;
  o[0] = (__bf16)fmaxf(a[0] + b0.x, 0.f);
  o[1] = (__bf16)fmaxf(a[1] + b0.y, 0.f);
  o[2] = (__bf16)fmaxf(a[2] + b0.z, 0.f);
  o[3] = (__bf16)fmaxf(a[3] + b0.w, 0.f);
  o[4] = (__bf16)fmaxf(a[4] + b1.x, 0.f);
  o[5] = (__bf16)fmaxf(a[5] + b1.y, 0.f);
  o[6] = (__bf16)fmaxf(a[6] + b1.z, 0.f);
  o[7] = (__bf16)fmaxf(a[7] + b1.w, 0.f);
  if (quar == 0) *(bf16x8*)(out + (size_t)w * 256 + ch0 + sl * 8) = o;
}

__global__ __launch_bounds__(256)
void spmm_bias_norm_b16(const int2* __restrict__ ecv, const int* __restrict__ start,
                        const __bf16* __restrict__ H, const float* __restrict__ bias,
                        float* __restrict__ out){
  const int w = (blockIdx.x * 256 + threadIdx.x) >> 6;
  const int lane = threadIdx.x & 63;
  const int quar = lane >> 4, sl = lane & 15;
  if (w >= NN) return;
  const int s = start[w], e = start[w + 1];
  float a[8];
  #pragma unroll
  for (int k = 0; k < 8; ++k) a[k] = 0.f;
  for (int base = s; base < e; base += 64){
    int2 cv = make_int2(0, 0);
    if (base + lane < e) cv = ecv[base + lane];
    const int m = min(64, e - base);
    for (int j2 = 0; 16 * j2 < m; ++j2){
      int cc[4]; float vv[4];
      #pragma unroll
      for (int u = 0; u < 4; ++u){
        const int idx = 16 * j2 + quar + 4 * u;
        cc[u] = __shfl(cv.x, idx);
        vv[u] = __int_as_float(__shfl(cv.y, idx));
        if (idx >= m){ cc[u] = 0; vv[u] = 0.f; }
      }
      bf16x8 h[4];
      #pragma unroll
      for (int u = 0; u < 4; ++u)
        h[u] = *(const bf16x8*)(H + (size_t)cc[u] * 128 + sl * 8);
      #pragma unroll
      for (int u = 0; u < 4; ++u)
        #pragma unroll
        for (int k = 0; k < 8; ++k) a[k] = fmaf(vv[u], (float)h[u][k], a[k]);
    }
  }
  #pragma unroll
  for (int k = 0; k < 8; ++k){
    a[k] += __shfl_xor(a[k], 32);
    a[k] += __shfl_xor(a[k], 16);
  }
  const float4 b0 = *(const float4*)(bias + sl * 8);
  const float4 b1 = *(const float4*)(bias + sl * 8 + 4);
  float f[8];
  f[0] = a[0] + b0.x; f[1] = a[1] + b0.y; f[2] = a[2] + b0.z; f[3] = a[3] + b0.w;
  f[4] = a[4] + b1.x; f[5] = a[5] + b1.y; f[6] = a[6] + b1.z; f[7] = a[7] + b1.w;
  float ss = 0.f;
  #pragma unroll
  for (int k = 0; k < 8; ++k) ss = fmaf(f[k], f[k], ss);
  #pragma unroll
  for (int m2 = 1; m2 < 16; m2 <<= 1) ss += __shfl_xor(ss, m2);
  const float inv = 1.f / fmaxf(sqrtf(ss), 1e-12f);
  if (quar == 0){
    float4 o0 = make_float4(f[0] * inv, f[1] * inv, f[2] * inv, f[3] * inv);
    float4 o1 = make_float4(f[4] * inv, f[5] * inv, f[6] * inv, f[7] * inv);
    *(float4*)(out + (size_t)w * 128 + sl * 8) = o0;
    *(float4*)(out + (size_t)w * 128 + sl * 8 + 4) = o1;
  }
}

// ---------------- launch ----------------
// ws layout (bytes):
//  xb  @ 0          [50048][320] bf16 = 32,030,720
//  W1b @ 32030720   [256][320]  bf16 =    163,840
//  W2b @ 32194560   [128][256]  bf16 =     65,536
//  h1  @ 32260096   [50048][256]bf16 = 25,624,576
//  h2  @ 57884672   [50048][256]bf16 = 25,624,576
//  h3  @ 83509248   [50048][128]bf16 = 12,812,288
//  ecv @ 96321536   800000 int2      =  6,400,000
//  rs  @ 102721536  50001 int        =    200,016
//  part@ 102921552  ~200 int (pad)
//  cur @ 102922368  50000 int        =    200,000
//  pos @ 103122368  800000 int       =  3,200,000   total ~106.3 MB
//  (pos now has OWN storage — round 12's h1-alias raced with scat_gemm)

extern "C" void kernel_launch(void* const* d_in, const int* in_sizes, int n_in,
                              void* d_out, int out_size, void* d_ws, size_t ws_size,
                              hipStream_t stream){
  const float* x    = (const float*)d_in[0];
  const int*   erow = (const int*)d_in[1];
  const int*   ecol = (const int*)d_in[2];
  const float* evalv= (const float*)d_in[3];
  const float* W1   = (const float*)d_in[4];
  const float* b1   = (const float*)d_in[5];
  const float* W2   = (const float*)d_in[6];
  const float* b2   = (const float*)d_in[7];
  float* out = (float*)d_out;

  char* ws = (char*)d_ws;
  __bf16* xb  = (__bf16*)(ws);
  __bf16* W1b = (__bf16*)(ws + 32030720);
  __bf16* W2b = (__bf16*)(ws + 32194560);
  __bf16* h1  = (__bf16*)(ws + 32260096);
  __bf16* h2  = (__bf16*)(ws + 57884672);
  __bf16* h3  = (__bf16*)(ws + 83509248);
  int2*   ecv = (int2*)(ws + 96321536);
  int*    rs  = (int*)(ws + 102721536);
  int*    part= (int*)(ws + 102921552);
  int*    cur = (int*)(ws + 102922368);
  int*    pos = (int*)(ws + 103122368);   // dedicated storage (no alias)

  // 1) zero cur
  k_zero<<<196, 256, 0, stream>>>(cur);
  // 2) rank (latency-bound) overlapped with x/W conversions (BW-bound)
  rank_conv<<<17315, 256, 0, stream>>>(erow, cur, pos, x, W1, W2, xb, W1b, W2b);
  // 3-4) scan
  k_scan1<<<196, 256, 0, stream>>>(cur, rs, part, NN);
  k_scan3<<<196, 256, 0, stream>>>(rs, part, NN);
  // 5) scatter overlapped with gemm1 (h1 = bf16(xb @ W1b^T))
  scat_gemm<5, 2><<<3131, 256, 0, stream>>>(erow, ecol, evalv, rs, pos, ecv,
                                            xb, W1b, h1, 320, 256);
  // 6) h2 = bf16(relu(A*h1 + b1)), both 128-ch halves in one dispatch
  spmm_relu_b16<<<25000, 256, 0, stream>>>(ecv, rs, h1, b1, h2);
  // 7) h3 = bf16(h2 @ W2b^T)
  gemm_bf16<4, 1><<<784, 256, 0, stream>>>(h2, W2b, h3, 256, 128);
  // 8) out = l2norm(A*h3 + b2)
  spmm_bias_norm_b16<<<12500, 256, 0, stream>>>(ecv, rs, h3, b2, out);
}